// Round 10
// baseline (1855.118 us; speedup 1.0000x reference)
//
#include <hip/hip_runtime.h>
#include <hip/hip_fp16.h>
#include <hip/hip_cooperative_groups.h>
#include <cstdint>
#include <cstddef>

#define NN 50000
#define NE 800000
#define HID 64
#define INF_ 128
#define BN_EPS 1e-5f
#define NGRP (NN / 8)        // 6250 node-octets for fp16 props
#define NG16 (NN / 16)       // 3125 node-16-groups for fp8 APPNP
#define SCAN_B 196           // ceil(50000/256)
#define NSLICE 32            // stats partial slices (contention fix)
#define NBKT 16              // degree buckets (chunk count = ceil(deg/8), capped)
#define COOP_B 512           // cooperative grid: 2 blocks/CU x 256 CU (headroom)

namespace cg = cooperative_groups;

typedef float floatx2 __attribute__((ext_vector_type(2)));

// ---------------- fp16 pack/unpack ----------------
__device__ __forceinline__ float4 h8_to_f4(float2 raw) {
    union { float f; __half2 h; } ua, ub;
    ua.f = raw.x; ub.f = raw.y;
    float2 fa = __half22float2(ua.h), fb = __half22float2(ub.h);
    return make_float4(fa.x, fa.y, fb.x, fb.y);
}
__device__ __forceinline__ float2 f4_to_h8(float4 v) {
    union { float f; __half2 h; } ua, ub;
    ua.h = __float22half2_rn(make_float2(v.x, v.y));
    ub.h = __float22half2_rn(make_float2(v.z, v.w));
    return make_float2(ua.f, ub.f);
}
struct f8 { float v[8]; };
__device__ __forceinline__ f8 h16_to_f8(float4 raw) {
    f8 r;
    union { float f; __half2 h; } u;
    float2 a;
    u.f = raw.x; a = __half22float2(u.h); r.v[0] = a.x; r.v[1] = a.y;
    u.f = raw.y; a = __half22float2(u.h); r.v[2] = a.x; r.v[3] = a.y;
    u.f = raw.z; a = __half22float2(u.h); r.v[4] = a.x; r.v[5] = a.y;
    u.f = raw.w; a = __half22float2(u.h); r.v[6] = a.x; r.v[7] = a.y;
    return r;
}
__device__ __forceinline__ float4 f8_to_h16(const f8& s) {
    union { float f; __half2 h; } u;
    float4 o;
    u.h = __float22half2_rn(make_float2(s.v[0], s.v[1])); o.x = u.f;
    u.h = __float22half2_rn(make_float2(s.v[2], s.v[3])); o.y = u.f;
    u.h = __float22half2_rn(make_float2(s.v[4], s.v[5])); o.z = u.f;
    u.h = __float22half2_rn(make_float2(s.v[6], s.v[7])); o.w = u.f;
    return o;
}

// ---------------- fp8 e4m3 (OCP, gfx950 HW cvt) pack/unpack ----------------
__device__ __forceinline__ void fp8x8_to_f(unsigned lo, unsigned hi, float out[8]) {
    floatx2 a = __builtin_amdgcn_cvt_pk_f32_fp8((int)lo, false);
    floatx2 b = __builtin_amdgcn_cvt_pk_f32_fp8((int)lo, true);
    floatx2 c = __builtin_amdgcn_cvt_pk_f32_fp8((int)hi, false);
    floatx2 d = __builtin_amdgcn_cvt_pk_f32_fp8((int)hi, true);
    out[0] = a[0]; out[1] = a[1]; out[2] = b[0]; out[3] = b[1];
    out[4] = c[0]; out[5] = c[1]; out[6] = d[0]; out[7] = d[1];
}
__device__ __forceinline__ void fp8x16_to_f(uint4 r, float out[16]) {
    fp8x8_to_f(r.x, r.y, out);
    fp8x8_to_f(r.z, r.w, out + 8);
}
__device__ __forceinline__ uint2 f_to_fp8x8(const float v[8]) {
    int w0 = __builtin_amdgcn_cvt_pk_fp8_f32(v[0], v[1], 0, false);
    w0 = __builtin_amdgcn_cvt_pk_fp8_f32(v[2], v[3], w0, true);
    int w1 = __builtin_amdgcn_cvt_pk_fp8_f32(v[4], v[5], 0, false);
    w1 = __builtin_amdgcn_cvt_pk_fp8_f32(v[6], v[7], w1, true);
    uint2 o; o.x = (unsigned)w0; o.y = (unsigned)w1;
    return o;
}
__device__ __forceinline__ uint4 f_to_fp8x16(const float v[16]) {
    uint2 a = f_to_fp8x8(v), b = f_to_fp8x8(v + 8);
    uint4 o; o.x = a.x; o.y = a.y; o.z = b.x; o.w = b.y;
    return o;
}

// ---------------- graph prep ----------------

__global__ void count_k(const int* __restrict__ dst, int* __restrict__ cnt) {
    int e = blockIdx.x * blockDim.x + threadIdx.x;
    if (e < NE) atomicAdd(&cnt[dst[e]], 1);
}

__global__ void dinv_k(const int* __restrict__ cnt, float* __restrict__ dinv) {
    int n = blockIdx.x * blockDim.x + threadIdx.x;
    if (n < NN) dinv[n] = rsqrtf((float)(cnt[n] + 1));   // +1 self-loop
}

// zero the padding row (index NN) of the gather arrays
__global__ void zrow_k(float4* __restrict__ tmpH, uint4* __restrict__ x8a,
                       uint4* __restrict__ x8b) {
    int t = threadIdx.x;
    if (t < 8) tmpH[(size_t)NN * 8 + t] = make_float4(0.f, 0.f, 0.f, 0.f);
    else if (t < 12) x8a[(size_t)NN * 4 + (t - 8)] = make_uint4(0, 0, 0, 0);
    else if (t < 16) x8b[(size_t)NN * 4 + (t - 12)] = make_uint4(0, 0, 0, 0);
}

// parallel scan of PADDED degrees ((deg+7)&~7) -> offs; 3 kernels
__global__ void scan1_k(const int* __restrict__ cnt, int* __restrict__ offs,
                        int* __restrict__ bsum) {
    __shared__ int sh[256];
    int t = threadIdx.x, i = blockIdx.x * 256 + t;
    int v = (i < NN) ? ((cnt[i] + 7) & ~7) : 0;
    sh[t] = v;
    __syncthreads();
    for (int d = 1; d < 256; d <<= 1) {
        int u = (t >= d) ? sh[t - d] : 0;
        __syncthreads();
        sh[t] += u;
        __syncthreads();
    }
    if (i < NN) offs[i] = sh[t] - v;
    if (t == 255) bsum[blockIdx.x] = sh[255];
}

__global__ void scan2_k(const int* __restrict__ bsum, int* __restrict__ bpre,
                        int* __restrict__ offs) {
    __shared__ int sh[256];
    int t = threadIdx.x;
    int v = (t < SCAN_B) ? bsum[t] : 0;
    sh[t] = v;
    __syncthreads();
    for (int d = 1; d < 256; d <<= 1) {
        int u = (t >= d) ? sh[t - d] : 0;
        __syncthreads();
        sh[t] += u;
        __syncthreads();
    }
    bpre[t] = sh[t] - v;
    if (t == 255) offs[NN] = sh[255];
}

__global__ void scan3_k(int* __restrict__ offs, const int* __restrict__ bpre) {
    int i = blockIdx.x * blockDim.x + threadIdx.x;
    if (i < NN) offs[i] += bpre[i >> 8];
}

__global__ void pad_k(const int* __restrict__ cnt, const int* __restrict__ offs,
                      int* __restrict__ edge1) {
    int n = blockIdx.x * blockDim.x + threadIdx.x;
    if (n >= NN) return;
    int e = offs[n] + cnt[n], e1 = offs[n + 1];
    for (; e < e1; ++e) edge1[e] = NN;   // pad -> all-zero row
}

// weight-free scatter: record = src index only (dinv folded into producers)
__global__ void scatter_k(const int* __restrict__ src, const int* __restrict__ dst,
                          const int* __restrict__ offs, int* __restrict__ cursor,
                          int* __restrict__ edge1) {
    int e = blockIdx.x * blockDim.x + threadIdx.x;
    if (e < NE) {
        int d = dst[e];
        int pos = offs[d] + atomicAdd(&cursor[d], 1);
        edge1[pos] = src[e];
    }
}

// ---- degree-bucketed node permutation ------------------------------------
__global__ void hist_k(const int* __restrict__ cnt, int* __restrict__ hist) {
    __shared__ int lh[NBKT];
    int t = threadIdx.x;
    if (t < NBKT) lh[t] = 0;
    __syncthreads();
    int n = blockIdx.x * 256 + t;
    if (n < NN) {
        int c = (cnt[n] + 7) >> 3;
        if (c > NBKT - 1) c = NBKT - 1;
        atomicAdd(&lh[c], 1);
    }
    __syncthreads();
    if (t < NBKT && lh[t]) atomicAdd(&hist[t], lh[t]);
}

__global__ void scan16_k(const int* __restrict__ hist, int* __restrict__ bcur) {
    if (threadIdx.x == 0) {
        int s = 0;
        for (int i = 0; i < NBKT; ++i) { bcur[i] = s; s += hist[i]; }
    }
}

__global__ void perm_k(const int* __restrict__ cnt, int* __restrict__ bcur,
                       int* __restrict__ perm) {
    __shared__ int lh[NBKT], lbase[NBKT];
    int t = threadIdx.x;
    if (t < NBKT) lh[t] = 0;
    __syncthreads();
    int n = blockIdx.x * 256 + t;
    int c = 0, r = 0;
    if (n < NN) {
        c = (cnt[n] + 7) >> 3;
        if (c > NBKT - 1) c = NBKT - 1;
        r = atomicAdd(&lh[c], 1);
    }
    __syncthreads();
    if (t < NBKT) lbase[t] = lh[t] ? atomicAdd(&bcur[t], lh[t]) : 0;
    __syncthreads();
    if (n < NN) perm[lbase[c] + r] = n;
}

// ------ dense matmul: Y[N,64] = dinv[n] * (X[N,K] @ W[K,64]), fp16 out -----
template <int K, bool HIN>
__global__ __launch_bounds__(256, 2) void mm_k(const void* __restrict__ Xv,
                                               const float* __restrict__ W,
                                               const float* __restrict__ dinv,
                                               float2* __restrict__ Y) {
    constexpr int RS = K + 4;            // LDS row stride (floats); keeps 16B align
    __shared__ float Xs[64 * RS];
    __shared__ float Ws[K * 64];
    const int t = threadIdx.x;
    const int n0 = blockIdx.x * 64;

    // stage W: K*16 float4, coalesced
    {
        const float4* Wg = (const float4*)W;
        for (int g2 = t; g2 < K * 16; g2 += 256) {
            int row = g2 >> 4, c4 = g2 & 15;
            *(float4*)&Ws[row * 64 + c4 * 4] = Wg[g2];
        }
    }
    // stage X tile (clamped rows for the tail block)
    if (HIN) {
        const float4* Xg = (const float4*)Xv;      // 8 halves per float4
        for (int g2 = t; g2 < 64 * (K / 8); g2 += 256) {
            int row = g2 / (K / 8), c8 = g2 % (K / 8);
            int rr = n0 + row; if (rr >= NN) rr = NN - 1;
            f8 v = h16_to_f8(Xg[(size_t)rr * (K / 8) + c8]);
            float* dp = &Xs[row * RS + c8 * 8];
#pragma unroll
            for (int j = 0; j < 8; ++j) dp[j] = v.v[j];
        }
    } else {
        const float4* Xg = (const float4*)Xv;
        for (int g2 = t; g2 < 64 * (K / 4); g2 += 256) {
            int row = g2 / (K / 4), c4 = g2 % (K / 4);
            int rr = n0 + row; if (rr >= NN) rr = NN - 1;
            *(float4*)&Xs[row * RS + c4 * 4] = Xg[(size_t)rr * (K / 4) + c4];
        }
    }
    __syncthreads();

    const int r0 = (t >> 4) << 2;
    const int c0 = (t & 15) << 2;
    float acc[4][4];
#pragma unroll
    for (int j = 0; j < 4; ++j)
#pragma unroll
        for (int c = 0; c < 4; ++c) acc[j][c] = 0.f;

#pragma unroll 8
    for (int kq = 0; kq < K / 4; ++kq) {
        float4 xv[4];
#pragma unroll
        for (int j = 0; j < 4; ++j)
            xv[j] = *(const float4*)&Xs[(r0 + j) * RS + kq * 4];
        float4 wv[4];
#pragma unroll
        for (int i = 0; i < 4; ++i)
            wv[i] = *(const float4*)&Ws[(kq * 4 + i) * 64 + c0];
#pragma unroll
        for (int j = 0; j < 4; ++j) {
            acc[j][0] = fmaf(xv[j].x, wv[0].x, acc[j][0]);
            acc[j][1] = fmaf(xv[j].x, wv[0].y, acc[j][1]);
            acc[j][2] = fmaf(xv[j].x, wv[0].z, acc[j][2]);
            acc[j][3] = fmaf(xv[j].x, wv[0].w, acc[j][3]);
            acc[j][0] = fmaf(xv[j].y, wv[1].x, acc[j][0]);
            acc[j][1] = fmaf(xv[j].y, wv[1].y, acc[j][1]);
            acc[j][2] = fmaf(xv[j].y, wv[1].z, acc[j][2]);
            acc[j][3] = fmaf(xv[j].y, wv[1].w, acc[j][3]);
            acc[j][0] = fmaf(xv[j].z, wv[2].x, acc[j][0]);
            acc[j][1] = fmaf(xv[j].z, wv[2].y, acc[j][1]);
            acc[j][2] = fmaf(xv[j].z, wv[2].z, acc[j][2]);
            acc[j][3] = fmaf(xv[j].z, wv[2].w, acc[j][3]);
            acc[j][0] = fmaf(xv[j].w, wv[3].x, acc[j][0]);
            acc[j][1] = fmaf(xv[j].w, wv[3].y, acc[j][1]);
            acc[j][2] = fmaf(xv[j].w, wv[3].z, acc[j][2]);
            acc[j][3] = fmaf(xv[j].w, wv[3].w, acc[j][3]);
        }
    }

#pragma unroll
    for (int j = 0; j < 4; ++j) {
        int rr = n0 + r0 + j;
        if (rr < NN) {
            float dn = dinv[rr];
            Y[(size_t)rr * 16 + (t & 15)] =
                f4_to_h8(make_float4(acc[j][0] * dn, acc[j][1] * dn,
                                     acc[j][2] * dn, acc[j][3] * dn));
        }
    }
}

// ---- fp16 propagate core: weight-free, 4+4 ping-pong (low-VGPR) -----------
__device__ __forceinline__ void prop_gather8(const float4* __restrict__ X4,
                                             const int* __restrict__ E,
                                             int e0, int e1, int fl, int slotbase,
                                             float acc[8]) {
    if (e0 >= e1) return;
    int d = E[e0 + fl];                 // 8 edge idxs for this slot group
    float4 ra[4];
#pragma unroll
    for (int i = 0; i < 4; ++i) {
        int s = __shfl(d, slotbase + i, 64);
        ra[i] = X4[(size_t)s * 8 + fl];
    }
    for (int e = e0; e < e1; e += 8) {
        float4 rb[4];
#pragma unroll
        for (int i = 0; i < 4; ++i) {
            int s = __shfl(d, slotbase + 4 + i, 64);
            rb[i] = X4[(size_t)s * 8 + fl];
        }
        bool more = (e + 8 < e1);
        if (more) d = E[e + 8 + fl];    // prefetch next block's indices
        __builtin_amdgcn_sched_barrier(0);
#pragma unroll
        for (int i = 0; i < 4; ++i) {
            f8 x = h16_to_f8(ra[i]);
#pragma unroll
            for (int j = 0; j < 8; ++j) acc[j] += x.v[j];
        }
        if (more) {
#pragma unroll
            for (int i = 0; i < 4; ++i) {
                int s = __shfl(d, slotbase + i, 64);
                ra[i] = X4[(size_t)s * 8 + fl];
            }
        }
        __builtin_amdgcn_sched_barrier(0);
#pragma unroll
        for (int i = 0; i < 4; ++i) {
            f8 x = h16_to_f8(rb[i]);
#pragma unroll
            for (int j = 0; j < 8; ++j) acc[j] += x.v[j];
        }
    }
}

// ---------------- propagate + bias + BN-stats (fp16 in, fp16 out) ----------
// X4 rows are pre-scaled by dinv[src]; out = dinv[dst]*sum + bias.
__global__ __launch_bounds__(256, 3) void prop_stats_k(
        const float4* __restrict__ X4, const int* __restrict__ offs,
        const int* __restrict__ edge1, const float* __restrict__ dinv,
        const float* __restrict__ bias, const int* __restrict__ perm,
        float4* __restrict__ Y4, float* __restrict__ stats) {
    const int lane = threadIdx.x & 63;
    const int wave = threadIdx.x >> 6;
    const int slot = lane >> 3;
    const int fl = lane & 7;
    const int slotbase = lane & 56;
    const int wid = blockIdx.x * 4 + wave;
    const int nw = gridDim.x * 4;

    float bias8[8];
    {
        float4 b0 = ((const float4*)bias)[fl * 2];
        float4 b1 = ((const float4*)bias)[fl * 2 + 1];
        bias8[0] = b0.x; bias8[1] = b0.y; bias8[2] = b0.z; bias8[3] = b0.w;
        bias8[4] = b1.x; bias8[5] = b1.y; bias8[6] = b1.z; bias8[7] = b1.w;
    }

    float s1[8], s2[8];
#pragma unroll
    for (int j = 0; j < 8; ++j) { s1[j] = 0.f; s2[j] = 0.f; }

    for (int g = wid; g < NGRP; g += nw) {
        int n = perm[g * 8 + slot];
        float dn = dinv[n];
        f8 self = h16_to_f8(X4[(size_t)n * 8 + fl]);   // already dinv[n]-scaled
        float acc[8];
#pragma unroll
        for (int j = 0; j < 8; ++j) acc[j] = self.v[j];
        int e0 = offs[n], e1 = offs[n + 1];
        prop_gather8(X4, edge1, e0, e1, fl, slotbase, acc);
        f8 o;
#pragma unroll
        for (int j = 0; j < 8; ++j) {
            float a = fmaf(dn, acc[j], bias8[j]);
            o.v[j] = a;
            s1[j] += a;
            s2[j] = fmaf(a, a, s2[j]);
        }
        Y4[(size_t)n * 8 + fl] = f8_to_h16(o);
    }

    // reduce across the 8 slots (lanes differing in bits 3,4,5)
#pragma unroll
    for (int m = 8; m <= 32; m <<= 1) {
#pragma unroll
        for (int j = 0; j < 8; ++j) {
            s1[j] += __shfl_xor(s1[j], m, 64);
            s2[j] += __shfl_xor(s2[j], m, 64);
        }
    }

    __shared__ float red[4][8][16];
    if (lane < 8) {
#pragma unroll
        for (int j = 0; j < 8; ++j) {
            red[wave][lane][j] = s1[j];
            red[wave][lane][8 + j] = s2[j];
        }
    }
    __syncthreads();
    int t = threadIdx.x;
    if (t < 128) {
        int j = t & 63;            // feature index
        int isq = t >> 6;          // 0 = sum, 1 = sumsq
        int fli = j >> 3, c = (j & 7) + isq * 8;
        float a = red[0][fli][c] + red[1][fli][c] + red[2][fli][c] + red[3][fli][c];
        atomicAdd(&stats[(blockIdx.x & (NSLICE - 1)) * 128 + isq * 64 + j], a);
    }
}

// ------- batchnorm + relu: fp16 in -> fp16 out; reduces 32 stat slices -----
// EMIT8: also emit fp8(dinv[n] * h) (pre-scaled for weight-free APPNP gather)
template <bool EMIT8>
__global__ __launch_bounds__(256) void bn_relu_k(
        const float4* __restrict__ Y4, const float* __restrict__ slices,
        const float* __restrict__ g, const float* __restrict__ be,
        float4* __restrict__ H4, uint2* __restrict__ X8,
        const float* __restrict__ dinv) {
    __shared__ float fs[128];
    int t = threadIdx.x;
    if (t < 128) {
        float s = 0.f;
#pragma unroll
        for (int k = 0; k < NSLICE; ++k) s += slices[k * 128 + t];
        fs[t] = s;
    }
    __syncthreads();
    int i = blockIdx.x * blockDim.x + t;
    if (i >= NN * 8) return;
    int fg = i & 7;                 // feats [fg*8, fg*8+8)
    const float invN = 1.f / (float)NN;
    f8 y = h16_to_f8(Y4[i]);
    float4 gv0 = ((const float4*)g)[fg * 2];
    float4 gv1 = ((const float4*)g)[fg * 2 + 1];
    float4 bv0 = ((const float4*)be)[fg * 2];
    float4 bv1 = ((const float4*)be)[fg * 2 + 1];
    float gv[8] = { gv0.x, gv0.y, gv0.z, gv0.w, gv1.x, gv1.y, gv1.z, gv1.w };
    float bv[8] = { bv0.x, bv0.y, bv0.z, bv0.w, bv1.x, bv1.y, bv1.z, bv1.w };
    f8 o;
#pragma unroll
    for (int j = 0; j < 8; ++j) {
        float m = fs[fg * 8 + j] * invN;
        float v = fs[64 + fg * 8 + j] * invN - m * m;
        float val = fmaf(gv[j] * rsqrtf(v + BN_EPS), y.v[j] - m, bv[j]);
        o.v[j] = val > 0.f ? val : 0.f;
    }
    H4[i] = f8_to_h16(o);
    if (EMIT8) {
        float dn = dinv[i >> 3];
        float sv[8];
#pragma unroll
        for (int j = 0; j < 8; ++j) sv[j] = dn * o.v[j];
        X8[i] = f_to_fp8x8(sv);
    }
}

// ---- shared fp8 APPNP hop body (weight-free, 4+4 ping-pong staging) -------
__device__ __forceinline__ void appnp_hop(
        const uint4* __restrict__ X8, uint4* __restrict__ Y8,
        const float4* __restrict__ H04, const int* __restrict__ offs,
        const int* __restrict__ edge1, const float* __restrict__ dinv,
        const int* __restrict__ perm, float4* __restrict__ Y16,
        bool out16, int wid, int slot, int fl, int quadbase) {
    int n = perm[wid * 16 + slot];
    float dn = dinv[n];
    float acc[16];
    {
        float self[16];
        fp8x16_to_f(X8[(size_t)n * 4 + fl], self);   // dinv[n]-scaled
#pragma unroll
        for (int j = 0; j < 16; ++j) acc[j] = self[j];
    }
    int e0 = offs[n], e1 = offs[n + 1];
    if (e0 < e1) {
        int2 d = ((const int2*)(edge1 + e0))[fl];   // 8 edges per slot group
        uint4 ra[4];
#pragma unroll
        for (int k = 0; k < 4; ++k) {
            int s = __shfl((k & 1) ? d.y : d.x, quadbase + (k >> 1), 64);
            ra[k] = X8[(size_t)s * 4 + fl];
        }
        for (int e = e0; e < e1; e += 8) {
            uint4 rb[4];
#pragma unroll
            for (int k = 0; k < 4; ++k) {
                int s = __shfl((k & 1) ? d.y : d.x, quadbase + 2 + (k >> 1), 64);
                rb[k] = X8[(size_t)s * 4 + fl];
            }
            bool more = (e + 8 < e1);
            if (more) d = ((const int2*)(edge1 + e + 8))[fl];
            __builtin_amdgcn_sched_barrier(0);
#pragma unroll
            for (int k = 0; k < 4; ++k) {
                float x[16];
                fp8x16_to_f(ra[k], x);
#pragma unroll
                for (int j = 0; j < 16; ++j) acc[j] += x[j];
            }
            if (more) {
#pragma unroll
                for (int k = 0; k < 4; ++k) {
                    int s = __shfl((k & 1) ? d.y : d.x, quadbase + (k >> 1), 64);
                    ra[k] = X8[(size_t)s * 4 + fl];
                }
            }
            __builtin_amdgcn_sched_barrier(0);
#pragma unroll
            for (int k = 0; k < 4; ++k) {
                float x[16];
                fp8x16_to_f(rb[k], x);
#pragma unroll
                for (int j = 0; j < 16; ++j) acc[j] += x[j];
            }
        }
    }
    // teleport: h0 fp16, feats [fl*16, fl*16+16)
    f8 ha = h16_to_f8(H04[(size_t)n * 8 + fl * 2]);
    f8 hb = h16_to_f8(H04[(size_t)n * 8 + fl * 2 + 1]);
    float o[16];
    float s = 0.9f * dn;
#pragma unroll
    for (int j = 0; j < 8; ++j) {
        o[j] = fmaf(s, acc[j], 0.1f * ha.v[j]);
        o[8 + j] = fmaf(s, acc[8 + j], 0.1f * hb.v[j]);
    }
    if (out16) {
        f8 lo, hi;
#pragma unroll
        for (int j = 0; j < 8; ++j) { lo.v[j] = o[j]; hi.v[j] = o[8 + j]; }
        Y16[(size_t)n * 8 + fl * 2] = f8_to_h16(lo);
        Y16[(size_t)n * 8 + fl * 2 + 1] = f8_to_h16(hi);
    } else {
        float so[16];
#pragma unroll
        for (int j = 0; j < 16; ++j) so[j] = dn * o[j];
        Y8[(size_t)n * 4 + fl] = f_to_fp8x16(so);
    }
}

// ---- per-hop fp8 APPNP kernel (fallback path) -----------------------------
template <bool OUT16>
__global__ __launch_bounds__(256, 3) void appnp8_k(
        const uint4* __restrict__ X8, const float4* __restrict__ H04,
        const int* __restrict__ offs, const int* __restrict__ edge1,
        const float* __restrict__ dinv, const int* __restrict__ perm,
        uint4* __restrict__ Y8, float4* __restrict__ Y16) {
    const int lane = threadIdx.x & 63;
    const int wave = threadIdx.x >> 6;
    const int wid = blockIdx.x * 4 + wave;
    if (wid >= NG16) return;
    appnp_hop(X8, Y8, H04, offs, edge1, dinv, perm, Y16, OUT16,
              wid, lane >> 2, lane & 3, lane & 60);
}

// ---- fused fp8 APPNP: all 10 hops in ONE cooperative kernel ---------------
// 512 blocks (2/CU at launch_bounds(256,2)) for co-residency headroom;
// grid.sync + threadfence (release+acquire) between hops.
__global__ __launch_bounds__(256, 2) void appnp_fused_k(
        uint4* __restrict__ x8a, uint4* __restrict__ x8b,
        const float4* __restrict__ H04,
        const int* __restrict__ offs, const int* __restrict__ edge1,
        const float* __restrict__ dinv, const int* __restrict__ perm,
        float4* __restrict__ Y16) {
    cg::grid_group grid = cg::this_grid();
    const int lane = threadIdx.x & 63;
    const int wave = threadIdx.x >> 6;
    const int slot = lane >> 2;
    const int fl = lane & 3;
    const int quadbase = lane & 60;
    const int wid0 = blockIdx.x * 4 + wave;
    const int nw = gridDim.x * 4;

    for (int hop = 0; hop < 10; ++hop) {
        const uint4* X8 = (hop & 1) ? x8b : x8a;
        uint4* Y8 = (hop & 1) ? x8a : x8b;
        const bool out16 = (hop == 9);
        for (int wid = wid0; wid < NG16; wid += nw)
            appnp_hop(X8, Y8, H04, offs, edge1, dinv, perm, Y16, out16,
                      wid, slot, fl, quadbase);
        if (hop < 9) {
            __threadfence();        // release: drain fp8 stores device-wide
            grid.sync();
            __threadfence();        // acquire: invalidate stale cached lines
        }
    }
}

// ---------------- FC + log_softmax (fp16 in, fp32 out) ----------------
__global__ __launch_bounds__(256) void final_k(const float2* __restrict__ H2,
                                               const float* __restrict__ Wfc,
                                               const float* __restrict__ bfc,
                                               float* __restrict__ out) {
    const int t = threadIdx.x;
    const int n0 = blockIdx.x * 64;
    const int r0 = (t >> 4) << 2;
    const int c0 = (t & 15) << 2;

    int r[4];
#pragma unroll
    for (int j = 0; j < 4; ++j) {
        int rr = n0 + r0 + j;
        r[j] = rr < NN ? rr : NN - 1;
    }
    const float2* Xr[4];
#pragma unroll
    for (int j = 0; j < 4; ++j) Xr[j] = H2 + (size_t)r[j] * 16;

    float4 bf = *(const float4*)(bfc + c0);
    float acc[4][4];
#pragma unroll
    for (int j = 0; j < 4; ++j) {
        acc[j][0] = bf.x; acc[j][1] = bf.y; acc[j][2] = bf.z; acc[j][3] = bf.w;
    }

#pragma unroll 4
    for (int kq = 0; kq < 16; ++kq) {
        float4 xv[4];
#pragma unroll
        for (int j = 0; j < 4; ++j) xv[j] = h8_to_f4(Xr[j][kq]);
        float4 wv[4];
#pragma unroll
        for (int i = 0; i < 4; ++i)
            wv[i] = *(const float4*)(Wfc + (size_t)(kq * 4 + i) * 64 + c0);
#pragma unroll
        for (int j = 0; j < 4; ++j) {
            acc[j][0] = fmaf(xv[j].x, wv[0].x, acc[j][0]);
            acc[j][1] = fmaf(xv[j].x, wv[0].y, acc[j][1]);
            acc[j][2] = fmaf(xv[j].x, wv[0].z, acc[j][2]);
            acc[j][3] = fmaf(xv[j].x, wv[0].w, acc[j][3]);
            acc[j][0] = fmaf(xv[j].y, wv[1].x, acc[j][0]);
            acc[j][1] = fmaf(xv[j].y, wv[1].y, acc[j][1]);
            acc[j][2] = fmaf(xv[j].y, wv[1].z, acc[j][2]);
            acc[j][3] = fmaf(xv[j].y, wv[1].w, acc[j][3]);
            acc[j][0] = fmaf(xv[j].z, wv[2].x, acc[j][0]);
            acc[j][1] = fmaf(xv[j].z, wv[2].y, acc[j][1]);
            acc[j][2] = fmaf(xv[j].z, wv[2].z, acc[j][2]);
            acc[j][3] = fmaf(xv[j].z, wv[2].w, acc[j][3]);
            acc[j][0] = fmaf(xv[j].w, wv[3].x, acc[j][0]);
            acc[j][1] = fmaf(xv[j].w, wv[3].y, acc[j][1]);
            acc[j][2] = fmaf(xv[j].w, wv[3].z, acc[j][2]);
            acc[j][3] = fmaf(xv[j].w, wv[3].w, acc[j][3]);
        }
    }

#pragma unroll
    for (int j = 0; j < 4; ++j) {
        float m = fmaxf(fmaxf(acc[j][0], acc[j][1]), fmaxf(acc[j][2], acc[j][3]));
#pragma unroll
        for (int d = 1; d <= 8; d <<= 1) m = fmaxf(m, __shfl_xor(m, d, 64));
        float s = expf(acc[j][0] - m) + expf(acc[j][1] - m) +
                  expf(acc[j][2] - m) + expf(acc[j][3] - m);
#pragma unroll
        for (int d = 1; d <= 8; d <<= 1) s += __shfl_xor(s, d, 64);
        float lse = m + logf(s);
        int rr = n0 + r0 + j;
        if (rr < NN)
            *(float4*)(out + (size_t)rr * 64 + c0) =
                make_float4(acc[j][0] - lse, acc[j][1] - lse,
                            acc[j][2] - lse, acc[j][3] - lse);
    }
}

// ---------------- host launch ----------------

static inline char* alignup(char* p, size_t a) {
    return (char*)(((uintptr_t)p + a - 1) & ~(uintptr_t)(a - 1));
}

extern "C" void kernel_launch(void* const* d_in, const int* in_sizes, int n_in,
                              void* d_out, int out_size, void* d_ws, size_t ws_size,
                              hipStream_t stream) {
    const float* x   = (const float*)d_in[0];
    const int*   ei  = (const int*)d_in[1];
    const float* W1  = (const float*)d_in[2];
    const float* b1  = (const float*)d_in[3];
    const float* W2  = (const float*)d_in[4];
    const float* b2  = (const float*)d_in[5];
    const float* Wx  = (const float*)d_in[6];
    const float* bx  = (const float*)d_in[7];
    const float* g1  = (const float*)d_in[8];
    const float* be1 = (const float*)d_in[9];
    const float* g2  = (const float*)d_in[10];
    const float* be2 = (const float*)d_in[11];
    const float* g3  = (const float*)d_in[12];
    const float* be3 = (const float*)d_in[13];
    const float* Wfc = (const float*)d_in[14];
    const float* bfc = (const float*)d_in[15];
    float* out = (float*)d_out;

    const int* srcA = ei;
    const int* dstA = ei + NE;

    char* p = (char*)d_ws;
    int*   deg    = (int*)p;   p += NN * 4;
    int*   cursor = (int*)p;   p += NN * 4;
    float* stats  = (float*)p; p += 4 * NSLICE * 128 * 4;   // 4 layers x 32 slices x 128
    int*   hist   = (int*)p;   p += NBKT * 4;               // zeroed each launch
    size_t zbytes = (size_t)(p - (char*)d_ws);
    p = alignup(p, 512);
    int*   offs  = (int*)p;    p += (NN + 4) * 4;   p = alignup(p, 512);
    float* dinv  = (float*)p;  p += NN * 4;         p = alignup(p, 512);
    int*   bsum  = (int*)p;    p += 256 * 4;
    int*   bpre  = (int*)p;    p += 256 * 4;
    int*   bcur  = (int*)p;    p += NBKT * 4;       p = alignup(p, 512);
    int*   perm  = (int*)p;    p += NN * 4;         p = alignup(p, 512);
    int*   edge1 = (int*)p;    p += ((size_t)NE + 8 * NN + 256) * 4; p = alignup(p, 512);
    float4* tmpH = (float4*)p; p += ((size_t)NN + 1) * 128; p = alignup(p, 512);
    float4* hbH  = (float4*)p; p += (size_t)NN * 128;       p = alignup(p, 512);
    float4* apH  = (float4*)p; p += (size_t)NN * 128;       p = alignup(p, 512);
    float4* pbH  = (float4*)p; p += (size_t)NN * 128;       p = alignup(p, 512);
    uint4*  x8a  = (uint4*)p;  p += ((size_t)NN + 1) * 64;  p = alignup(p, 512);
    uint4*  x8b  = (uint4*)p;  p += ((size_t)NN + 1) * 64;

    hipMemsetAsync(d_ws, 0, zbytes, stream);

    count_k<<<(NE + 255) / 256, 256, 0, stream>>>(dstA, deg);
    dinv_k<<<(NN + 255) / 256, 256, 0, stream>>>(deg, dinv);
    zrow_k<<<1, 64, 0, stream>>>(tmpH, x8a, x8b);
    hist_k<<<SCAN_B, 256, 0, stream>>>(deg, hist);
    scan16_k<<<1, 64, 0, stream>>>(hist, bcur);
    perm_k<<<SCAN_B, 256, 0, stream>>>(deg, bcur, perm);
    scan1_k<<<SCAN_B, 256, 0, stream>>>(deg, offs, bsum);
    scan2_k<<<1, 256, 0, stream>>>(bsum, bpre, offs);
    scan3_k<<<(NN + 255) / 256, 256, 0, stream>>>(offs, bpre);
    pad_k<<<(NN + 255) / 256, 256, 0, stream>>>(deg, offs, edge1);
    scatter_k<<<(NE + 255) / 256, 256, 0, stream>>>(srcA, dstA, offs, cursor, edge1);

    const int MMG = (NN + 63) / 64;          // 782
    const int PG  = (NGRP + 3) / 4;          // 1563: one octet per wave
    const int AG  = (NG16 + 3) / 4;          // 782:  one 16-group per wave
    const int BNG = (NN * 8 + 255) / 256;    // 1563
    const int SL  = NSLICE * 128;            // floats per layer slice block

    mm_k<INF_, false><<<MMG, 256, 0, stream>>>(x, W1, dinv, (float2*)tmpH);
    prop_stats_k<<<PG, 256, 0, stream>>>(tmpH, offs, edge1, dinv, b1, perm, pbH, stats + 0 * SL);
    bn_relu_k<false><<<BNG, 256, 0, stream>>>(pbH, stats + 0 * SL, g1, be1, hbH, nullptr, dinv);

    mm_k<HID, true><<<MMG, 256, 0, stream>>>(hbH, W2, dinv, (float2*)tmpH);
    prop_stats_k<<<PG, 256, 0, stream>>>(tmpH, offs, edge1, dinv, b2, perm, pbH, stats + 1 * SL);
    bn_relu_k<false><<<BNG, 256, 0, stream>>>(pbH, stats + 1 * SL, g2, be2, hbH, nullptr, dinv);

    // extra layer 0
    mm_k<HID, true><<<MMG, 256, 0, stream>>>(hbH, Wx + (size_t)0 * 64 * 64, dinv, (float2*)tmpH);
    prop_stats_k<<<PG, 256, 0, stream>>>(tmpH, offs, edge1, dinv, bx + (size_t)0 * 64, perm,
                                         pbH, stats + 2 * SL);
    bn_relu_k<false><<<BNG, 256, 0, stream>>>(pbH, stats + 2 * SL, g3, be3, hbH, nullptr, dinv);

    // extra layer 1: fuse the fp8(dinv*h) conversion into the BN/ReLU epilogue
    mm_k<HID, true><<<MMG, 256, 0, stream>>>(hbH, Wx + (size_t)1 * 64 * 64, dinv, (float2*)tmpH);
    prop_stats_k<<<PG, 256, 0, stream>>>(tmpH, offs, edge1, dinv, bx + (size_t)1 * 64, perm,
                                         pbH, stats + 3 * SL);
    bn_relu_k<true><<<BNG, 256, 0, stream>>>(pbH, stats + 3 * SL, g3, be3, hbH, (uint2*)x8a, dinv);

    // fused APPNP (10 hops, 1 cooperative kernel); fallback to per-hop loop
    {
        uint4* pa = x8a; uint4* pb = x8b;
        const float4* ph = hbH;
        const int* po = offs; const int* pe = edge1;
        const float* pd = dinv; const int* pp = perm;
        float4* py = apH;
        void* cargs[] = { &pa, &pb, &ph, &po, &pe, &pd, &pp, &py };
        hipError_t cerr = hipLaunchCooperativeKernel(
            (const void*)appnp_fused_k, dim3(COOP_B), dim3(256), cargs, 0, stream);
        if (cerr != hipSuccess) {
            const uint4* cur8 = x8a;
            for (int it = 0; it < 9; ++it) {
                uint4* o8 = (cur8 == x8a) ? x8b : x8a;
                appnp8_k<false><<<AG, 256, 0, stream>>>(cur8, hbH, offs, edge1,
                                                        dinv, perm, o8, nullptr);
                cur8 = o8;
            }
            appnp8_k<true><<<AG, 256, 0, stream>>>(cur8, hbH, offs, edge1,
                                                   dinv, perm, nullptr, apH);
        }
    }

    final_k<<<MMG, 256, 0, stream>>>((const float2*)apH, Wfc, bfc, out);
}

// Round 11
// 476.371 us; speedup vs baseline: 3.8943x; 3.8943x over previous
//
#include <hip/hip_runtime.h>
#include <hip/hip_fp16.h>
#include <cstdint>
#include <cstddef>

#define NN 50000
#define NE 800000
#define HID 64
#define INF_ 128
#define BN_EPS 1e-5f
#define NGRP (NN / 8)        // 6250 node-octets for fp16 props
#define NG16 (NN / 16)       // 3125 node-16-groups for fp8 APPNP
#define SCAN_B 196           // ceil(50000/256)
#define NSLICE 32            // stats partial slices (contention fix)
#define NBKT 16              // degree buckets (chunk count = ceil(deg/8), capped)
#define NBIN 196             // dst bins of 256 nodes (50000/256 -> 196)
#define EPB 2048             // edges per binscat block

typedef float floatx2 __attribute__((ext_vector_type(2)));

// ---------------- fp16 pack/unpack ----------------
__device__ __forceinline__ float4 h8_to_f4(float2 raw) {
    union { float f; __half2 h; } ua, ub;
    ua.f = raw.x; ub.f = raw.y;
    float2 fa = __half22float2(ua.h), fb = __half22float2(ub.h);
    return make_float4(fa.x, fa.y, fb.x, fb.y);
}
__device__ __forceinline__ float2 f4_to_h8(float4 v) {
    union { float f; __half2 h; } ua, ub;
    ua.h = __float22half2_rn(make_float2(v.x, v.y));
    ub.h = __float22half2_rn(make_float2(v.z, v.w));
    return make_float2(ua.f, ub.f);
}
struct f8 { float v[8]; };
__device__ __forceinline__ f8 h16_to_f8(float4 raw) {
    f8 r;
    union { float f; __half2 h; } u;
    float2 a;
    u.f = raw.x; a = __half22float2(u.h); r.v[0] = a.x; r.v[1] = a.y;
    u.f = raw.y; a = __half22float2(u.h); r.v[2] = a.x; r.v[3] = a.y;
    u.f = raw.z; a = __half22float2(u.h); r.v[4] = a.x; r.v[5] = a.y;
    u.f = raw.w; a = __half22float2(u.h); r.v[6] = a.x; r.v[7] = a.y;
    return r;
}
__device__ __forceinline__ float4 f8_to_h16(const f8& s) {
    union { float f; __half2 h; } u;
    float4 o;
    u.h = __float22half2_rn(make_float2(s.v[0], s.v[1])); o.x = u.f;
    u.h = __float22half2_rn(make_float2(s.v[2], s.v[3])); o.y = u.f;
    u.h = __float22half2_rn(make_float2(s.v[4], s.v[5])); o.z = u.f;
    u.h = __float22half2_rn(make_float2(s.v[6], s.v[7])); o.w = u.f;
    return o;
}

// ---------------- fp8 e4m3 (OCP, gfx950 HW cvt) pack/unpack ----------------
__device__ __forceinline__ void fp8x8_to_f(unsigned lo, unsigned hi, float out[8]) {
    floatx2 a = __builtin_amdgcn_cvt_pk_f32_fp8((int)lo, false);
    floatx2 b = __builtin_amdgcn_cvt_pk_f32_fp8((int)lo, true);
    floatx2 c = __builtin_amdgcn_cvt_pk_f32_fp8((int)hi, false);
    floatx2 d = __builtin_amdgcn_cvt_pk_f32_fp8((int)hi, true);
    out[0] = a[0]; out[1] = a[1]; out[2] = b[0]; out[3] = b[1];
    out[4] = c[0]; out[5] = c[1]; out[6] = d[0]; out[7] = d[1];
}
__device__ __forceinline__ void fp8x16_to_f(uint4 r, float out[16]) {
    fp8x8_to_f(r.x, r.y, out);
    fp8x8_to_f(r.z, r.w, out + 8);
}
__device__ __forceinline__ uint2 f_to_fp8x8(const float v[8]) {
    int w0 = __builtin_amdgcn_cvt_pk_fp8_f32(v[0], v[1], 0, false);
    w0 = __builtin_amdgcn_cvt_pk_fp8_f32(v[2], v[3], w0, true);
    int w1 = __builtin_amdgcn_cvt_pk_fp8_f32(v[4], v[5], 0, false);
    w1 = __builtin_amdgcn_cvt_pk_fp8_f32(v[6], v[7], w1, true);
    uint2 o; o.x = (unsigned)w0; o.y = (unsigned)w1;
    return o;
}
__device__ __forceinline__ uint4 f_to_fp8x16(const float v[16]) {
    uint2 a = f_to_fp8x8(v), b = f_to_fp8x8(v + 8);
    uint4 o; o.x = a.x; o.y = a.y; o.z = b.x; o.w = b.y;
    return o;
}

// ---------------- graph prep ----------------

__global__ void count_k(const int* __restrict__ dst, int* __restrict__ cnt) {
    int e = blockIdx.x * blockDim.x + threadIdx.x;
    if (e < NE) atomicAdd(&cnt[dst[e]], 1);
}

__global__ void dinv_k(const int* __restrict__ cnt, float* __restrict__ dinv) {
    int n = blockIdx.x * blockDim.x + threadIdx.x;
    if (n < NN) dinv[n] = rsqrtf((float)(cnt[n] + 1));   // +1 self-loop
}

// zero the padding row (index NN) of the gather arrays
__global__ void zrow_k(float4* __restrict__ tmpH, uint4* __restrict__ x8a,
                       uint4* __restrict__ x8b) {
    int t = threadIdx.x;
    if (t < 8) tmpH[(size_t)NN * 8 + t] = make_float4(0.f, 0.f, 0.f, 0.f);
    else if (t < 12) x8a[(size_t)NN * 4 + (t - 8)] = make_uint4(0, 0, 0, 0);
    else if (t < 16) x8b[(size_t)NN * 4 + (t - 12)] = make_uint4(0, 0, 0, 0);
}

// parallel scan of PADDED degrees ((deg+7)&~7) -> offs; 3 kernels
__global__ void scan1_k(const int* __restrict__ cnt, int* __restrict__ offs,
                        int* __restrict__ bsum) {
    __shared__ int sh[256];
    int t = threadIdx.x, i = blockIdx.x * 256 + t;
    int v = (i < NN) ? ((cnt[i] + 7) & ~7) : 0;
    sh[t] = v;
    __syncthreads();
    for (int d = 1; d < 256; d <<= 1) {
        int u = (t >= d) ? sh[t - d] : 0;
        __syncthreads();
        sh[t] += u;
        __syncthreads();
    }
    if (i < NN) offs[i] = sh[t] - v;
    if (t == 255) bsum[blockIdx.x] = sh[255];
}

__global__ void scan2_k(const int* __restrict__ bsum, int* __restrict__ bpre,
                        int* __restrict__ offs) {
    __shared__ int sh[256];
    int t = threadIdx.x;
    int v = (t < SCAN_B) ? bsum[t] : 0;
    sh[t] = v;
    __syncthreads();
    for (int d = 1; d < 256; d <<= 1) {
        int u = (t >= d) ? sh[t - d] : 0;
        __syncthreads();
        sh[t] += u;
        __syncthreads();
    }
    bpre[t] = sh[t] - v;
    if (t == 255) offs[NN] = sh[255];
}

__global__ void scan3_k(int* __restrict__ offs, const int* __restrict__ bpre) {
    int i = blockIdx.x * blockDim.x + threadIdx.x;
    if (i < NN) offs[i] += bpre[i >> 8];
}

__global__ void pad_k(const int* __restrict__ cnt, const int* __restrict__ offs,
                      int* __restrict__ edge1) {
    int n = blockIdx.x * blockDim.x + threadIdx.x;
    if (n >= NN) return;
    int e = offs[n] + cnt[n], e1 = offs[n + 1];
    for (; e < e1; ++e) edge1[e] = NN;   // pad -> all-zero row
}

// ---- binned edge scatter (kills 8x write amplification of random 4B) ------
// binhist: bincnt[b] = sum of in-degrees over nodes [b*256, b*256+256)
__global__ void binhist_k(const int* __restrict__ cnt, int* __restrict__ bincnt) {
    __shared__ int sh[256];
    int b = blockIdx.x, t = threadIdx.x;
    int n = b * 256 + t;
    sh[t] = (n < NN) ? cnt[n] : 0;
    __syncthreads();
    for (int d = 128; d > 0; d >>= 1) {
        if (t < d) sh[t] += sh[t + d];
        __syncthreads();
    }
    if (t == 0) bincnt[b] = sh[0];
}

// scan bins -> boffs (exclusive) and init bcur
__global__ void scanbin_k(const int* __restrict__ bincnt, int* __restrict__ boffs,
                          int* __restrict__ bcur) {
    __shared__ int sh[256];
    int t = threadIdx.x;
    int v = (t < NBIN) ? bincnt[t] : 0;
    sh[t] = v;
    __syncthreads();
    for (int d = 1; d < 256; d <<= 1) {
        int u = (t >= d) ? sh[t - d] : 0;
        __syncthreads();
        sh[t] += u;
        __syncthreads();
    }
    boffs[t] = sh[t] - v;
    bcur[t] = sh[t] - v;
    if (t == 255) boffs[NBIN] = sh[255];
}

// pass A: block-local LDS bucket sort of EPB edges into NBIN dst-bins,
// then contiguous-run writes into the global pairs array.
__global__ __launch_bounds__(256) void binscat_k(
        const int* __restrict__ src, const int* __restrict__ dst,
        int* __restrict__ bcur, int2* __restrict__ pairs) {
    __shared__ int lcnt[256], lscan[256], lexc[256], gbase[256];
    __shared__ int2 stage[EPB];
    const int t = threadIdx.x;
    const int base = blockIdx.x * EPB;
    lcnt[t] = 0;
    __syncthreads();
    int2 mypair[EPB / 256];
    int mybin[EPB / 256], myr[EPB / 256];
#pragma unroll
    for (int i = 0; i < EPB / 256; ++i) {
        int e = base + i * 256 + t;
        if (e < NE) {
            int s = src[e], d = dst[e];
            mypair[i] = make_int2(s, d);
            mybin[i] = d >> 8;
            myr[i] = atomicAdd(&lcnt[mybin[i]], 1);
        } else mybin[i] = -1;
    }
    __syncthreads();
    lscan[t] = lcnt[t];
    __syncthreads();
    for (int d = 1; d < 256; d <<= 1) {
        int u = (t >= d) ? lscan[t - d] : 0;
        __syncthreads();
        lscan[t] += u;
        __syncthreads();
    }
    lexc[t] = lscan[t] - lcnt[t];
    if (lcnt[t] > 0) gbase[t] = atomicAdd(&bcur[t], lcnt[t]);
    __syncthreads();
#pragma unroll
    for (int i = 0; i < EPB / 256; ++i)
        if (mybin[i] >= 0) stage[lexc[mybin[i]] + myr[i]] = mypair[i];
    __syncthreads();
    const int total = lscan[255];
#pragma unroll
    for (int i = 0; i < EPB / 256; ++i) {
        int s = i * 256 + t;
        if (s < total) {
            int2 pr = stage[s];
            int b = pr.y >> 8;
            pairs[(size_t)gbase[b] + (s - lexc[b])] = pr;   // contiguous runs
        }
    }
}

// pass B: one block per bin; place edges into CSR. Random writes confined to
// the bin's ~20KB CSR window -> L2-coalesced full lines to HBM.
__global__ __launch_bounds__(256) void binplace_k(
        const int* __restrict__ boffs, const int2* __restrict__ pairs,
        const int* __restrict__ offs, int* __restrict__ edge1) {
    __shared__ int lcur[256];
    const int b = blockIdx.x, t = threadIdx.x;
    lcur[t] = 0;
    __syncthreads();
    int s0 = boffs[b], s1 = boffs[b + 1];
    for (int s = s0 + t; s < s1; s += 256) {
        int2 pr = pairs[s];
        int d = pr.y;
        int slot = atomicAdd(&lcur[d & 255], 1);
        edge1[offs[d] + slot] = pr.x;
    }
}

// ---- degree-bucketed node permutation ------------------------------------
__global__ void hist_k(const int* __restrict__ cnt, int* __restrict__ hist) {
    __shared__ int lh[NBKT];
    int t = threadIdx.x;
    if (t < NBKT) lh[t] = 0;
    __syncthreads();
    int n = blockIdx.x * 256 + t;
    if (n < NN) {
        int c = (cnt[n] + 7) >> 3;
        if (c > NBKT - 1) c = NBKT - 1;
        atomicAdd(&lh[c], 1);
    }
    __syncthreads();
    if (t < NBKT && lh[t]) atomicAdd(&hist[t], lh[t]);
}

__global__ void scan16_k(const int* __restrict__ hist, int* __restrict__ bcur) {
    if (threadIdx.x == 0) {
        int s = 0;
        for (int i = 0; i < NBKT; ++i) { bcur[i] = s; s += hist[i]; }
    }
}

__global__ void perm_k(const int* __restrict__ cnt, int* __restrict__ bcur,
                       int* __restrict__ perm) {
    __shared__ int lh[NBKT], lbase[NBKT];
    int t = threadIdx.x;
    if (t < NBKT) lh[t] = 0;
    __syncthreads();
    int n = blockIdx.x * 256 + t;
    int c = 0, r = 0;
    if (n < NN) {
        c = (cnt[n] + 7) >> 3;
        if (c > NBKT - 1) c = NBKT - 1;
        r = atomicAdd(&lh[c], 1);
    }
    __syncthreads();
    if (t < NBKT) lbase[t] = lh[t] ? atomicAdd(&bcur[t], lh[t]) : 0;
    __syncthreads();
    if (n < NN) perm[lbase[c] + r] = n;
}

// ------ dense matmul: Y[N,64] = dinv[n] * (X[N,K] @ W[K,64]), fp16 out -----
template <int K, bool HIN>
__global__ __launch_bounds__(256, 2) void mm_k(const void* __restrict__ Xv,
                                               const float* __restrict__ W,
                                               const float* __restrict__ dinv,
                                               float2* __restrict__ Y) {
    constexpr int RS = K + 4;            // LDS row stride (floats); keeps 16B align
    __shared__ float Xs[64 * RS];
    __shared__ float Ws[K * 64];
    const int t = threadIdx.x;
    const int n0 = blockIdx.x * 64;

    // stage W: K*16 float4, coalesced
    {
        const float4* Wg = (const float4*)W;
        for (int g2 = t; g2 < K * 16; g2 += 256) {
            int row = g2 >> 4, c4 = g2 & 15;
            *(float4*)&Ws[row * 64 + c4 * 4] = Wg[g2];
        }
    }
    // stage X tile (clamped rows for the tail block)
    if (HIN) {
        const float4* Xg = (const float4*)Xv;      // 8 halves per float4
        for (int g2 = t; g2 < 64 * (K / 8); g2 += 256) {
            int row = g2 / (K / 8), c8 = g2 % (K / 8);
            int rr = n0 + row; if (rr >= NN) rr = NN - 1;
            f8 v = h16_to_f8(Xg[(size_t)rr * (K / 8) + c8]);
            float* dp = &Xs[row * RS + c8 * 8];
#pragma unroll
            for (int j = 0; j < 8; ++j) dp[j] = v.v[j];
        }
    } else {
        const float4* Xg = (const float4*)Xv;
        for (int g2 = t; g2 < 64 * (K / 4); g2 += 256) {
            int row = g2 / (K / 4), c4 = g2 % (K / 4);
            int rr = n0 + row; if (rr >= NN) rr = NN - 1;
            *(float4*)&Xs[row * RS + c4 * 4] = Xg[(size_t)rr * (K / 4) + c4];
        }
    }
    __syncthreads();

    const int r0 = (t >> 4) << 2;
    const int c0 = (t & 15) << 2;
    float acc[4][4];
#pragma unroll
    for (int j = 0; j < 4; ++j)
#pragma unroll
        for (int c = 0; c < 4; ++c) acc[j][c] = 0.f;

#pragma unroll 8
    for (int kq = 0; kq < K / 4; ++kq) {
        float4 xv[4];
#pragma unroll
        for (int j = 0; j < 4; ++j)
            xv[j] = *(const float4*)&Xs[(r0 + j) * RS + kq * 4];
        float4 wv[4];
#pragma unroll
        for (int i = 0; i < 4; ++i)
            wv[i] = *(const float4*)&Ws[(kq * 4 + i) * 64 + c0];
#pragma unroll
        for (int j = 0; j < 4; ++j) {
            acc[j][0] = fmaf(xv[j].x, wv[0].x, acc[j][0]);
            acc[j][1] = fmaf(xv[j].x, wv[0].y, acc[j][1]);
            acc[j][2] = fmaf(xv[j].x, wv[0].z, acc[j][2]);
            acc[j][3] = fmaf(xv[j].x, wv[0].w, acc[j][3]);
            acc[j][0] = fmaf(xv[j].y, wv[1].x, acc[j][0]);
            acc[j][1] = fmaf(xv[j].y, wv[1].y, acc[j][1]);
            acc[j][2] = fmaf(xv[j].y, wv[1].z, acc[j][2]);
            acc[j][3] = fmaf(xv[j].y, wv[1].w, acc[j][3]);
            acc[j][0] = fmaf(xv[j].z, wv[2].x, acc[j][0]);
            acc[j][1] = fmaf(xv[j].z, wv[2].y, acc[j][1]);
            acc[j][2] = fmaf(xv[j].z, wv[2].z, acc[j][2]);
            acc[j][3] = fmaf(xv[j].z, wv[2].w, acc[j][3]);
            acc[j][0] = fmaf(xv[j].w, wv[3].x, acc[j][0]);
            acc[j][1] = fmaf(xv[j].w, wv[3].y, acc[j][1]);
            acc[j][2] = fmaf(xv[j].w, wv[3].z, acc[j][2]);
            acc[j][3] = fmaf(xv[j].w, wv[3].w, acc[j][3]);
        }
    }

#pragma unroll
    for (int j = 0; j < 4; ++j) {
        int rr = n0 + r0 + j;
        if (rr < NN) {
            float dn = dinv[rr];
            Y[(size_t)rr * 16 + (t & 15)] =
                f4_to_h8(make_float4(acc[j][0] * dn, acc[j][1] * dn,
                                     acc[j][2] * dn, acc[j][3] * dn));
        }
    }
}

// ---- fused BN+ReLU -> matmul (K=64): replaces 3 bn_relu passes ------------
// reads pre-BN fp16 Y4in + per-layer stat slices; applies BN+ReLU during
// LDS staging; then Y = dinv[n] * (H @ W).
__global__ __launch_bounds__(256, 2) void mm_bn_k(
        const float4* __restrict__ Y4in, const float* __restrict__ slices,
        const float* __restrict__ gg, const float* __restrict__ be,
        const float* __restrict__ W, const float* __restrict__ dinv,
        float2* __restrict__ Y) {
    constexpr int K = 64, RS = K + 4;
    __shared__ float Xs[64 * RS];
    __shared__ float Ws[K * 64];
    __shared__ float fs[128], gs[64], bs[64];
    const int t = threadIdx.x;
    const int n0 = blockIdx.x * 64;

    if (t < 128) {
        float s = 0.f;
#pragma unroll
        for (int k = 0; k < NSLICE; ++k) s += slices[k * 128 + t];
        fs[t] = s;
    } else if (t < 192) {
        gs[t - 128] = gg[t - 128];
    } else {
        bs[t - 192] = be[t - 192];
    }
    {
        const float4* Wg = (const float4*)W;
        for (int g2 = t; g2 < K * 16; g2 += 256) {
            int row = g2 >> 4, c4 = g2 & 15;
            *(float4*)&Ws[row * 64 + c4 * 4] = Wg[g2];
        }
    }
    __syncthreads();

    const float invN = 1.f / (float)NN;
    for (int g2 = t; g2 < 64 * 8; g2 += 256) {
        int row = g2 >> 3, c8 = g2 & 7;
        int rr = n0 + row; if (rr >= NN) rr = NN - 1;
        f8 v = h16_to_f8(Y4in[(size_t)rr * 8 + c8]);
        float* dp = &Xs[row * RS + c8 * 8];
#pragma unroll
        for (int j = 0; j < 8; ++j) {
            int f = c8 * 8 + j;
            float m = fs[f] * invN;
            float va = fs[64 + f] * invN - m * m;
            float val = fmaf(gs[f] * rsqrtf(va + BN_EPS), v.v[j] - m, bs[f]);
            dp[j] = val > 0.f ? val : 0.f;
        }
    }
    __syncthreads();

    const int r0 = (t >> 4) << 2;
    const int c0 = (t & 15) << 2;
    float acc[4][4];
#pragma unroll
    for (int j = 0; j < 4; ++j)
#pragma unroll
        for (int c = 0; c < 4; ++c) acc[j][c] = 0.f;

#pragma unroll 8
    for (int kq = 0; kq < K / 4; ++kq) {
        float4 xv[4];
#pragma unroll
        for (int j = 0; j < 4; ++j)
            xv[j] = *(const float4*)&Xs[(r0 + j) * RS + kq * 4];
        float4 wv[4];
#pragma unroll
        for (int i = 0; i < 4; ++i)
            wv[i] = *(const float4*)&Ws[(kq * 4 + i) * 64 + c0];
#pragma unroll
        for (int j = 0; j < 4; ++j) {
            acc[j][0] = fmaf(xv[j].x, wv[0].x, acc[j][0]);
            acc[j][1] = fmaf(xv[j].x, wv[0].y, acc[j][1]);
            acc[j][2] = fmaf(xv[j].x, wv[0].z, acc[j][2]);
            acc[j][3] = fmaf(xv[j].x, wv[0].w, acc[j][3]);
            acc[j][0] = fmaf(xv[j].y, wv[1].x, acc[j][0]);
            acc[j][1] = fmaf(xv[j].y, wv[1].y, acc[j][1]);
            acc[j][2] = fmaf(xv[j].y, wv[1].z, acc[j][2]);
            acc[j][3] = fmaf(xv[j].y, wv[1].w, acc[j][3]);
            acc[j][0] = fmaf(xv[j].z, wv[2].x, acc[j][0]);
            acc[j][1] = fmaf(xv[j].z, wv[2].y, acc[j][1]);
            acc[j][2] = fmaf(xv[j].z, wv[2].z, acc[j][2]);
            acc[j][3] = fmaf(xv[j].z, wv[2].w, acc[j][3]);
            acc[j][0] = fmaf(xv[j].w, wv[3].x, acc[j][0]);
            acc[j][1] = fmaf(xv[j].w, wv[3].y, acc[j][1]);
            acc[j][2] = fmaf(xv[j].w, wv[3].z, acc[j][2]);
            acc[j][3] = fmaf(xv[j].w, wv[3].w, acc[j][3]);
        }
    }

#pragma unroll
    for (int j = 0; j < 4; ++j) {
        int rr = n0 + r0 + j;
        if (rr < NN) {
            float dn = dinv[rr];
            Y[(size_t)rr * 16 + (t & 15)] =
                f4_to_h8(make_float4(acc[j][0] * dn, acc[j][1] * dn,
                                     acc[j][2] * dn, acc[j][3] * dn));
        }
    }
}

// ---- fp16 propagate core: weight-free, 4+4 ping-pong (low-VGPR) -----------
__device__ __forceinline__ void prop_gather8(const float4* __restrict__ X4,
                                             const int* __restrict__ E,
                                             int e0, int e1, int fl, int slotbase,
                                             float acc[8]) {
    if (e0 >= e1) return;
    int d = E[e0 + fl];                 // 8 edge idxs for this slot group
    float4 ra[4];
#pragma unroll
    for (int i = 0; i < 4; ++i) {
        int s = __shfl(d, slotbase + i, 64);
        ra[i] = X4[(size_t)s * 8 + fl];
    }
    for (int e = e0; e < e1; e += 8) {
        float4 rb[4];
#pragma unroll
        for (int i = 0; i < 4; ++i) {
            int s = __shfl(d, slotbase + 4 + i, 64);
            rb[i] = X4[(size_t)s * 8 + fl];
        }
        bool more = (e + 8 < e1);
        if (more) d = E[e + 8 + fl];    // prefetch next block's indices
        __builtin_amdgcn_sched_barrier(0);
#pragma unroll
        for (int i = 0; i < 4; ++i) {
            f8 x = h16_to_f8(ra[i]);
#pragma unroll
            for (int j = 0; j < 8; ++j) acc[j] += x.v[j];
        }
        if (more) {
#pragma unroll
            for (int i = 0; i < 4; ++i) {
                int s = __shfl(d, slotbase + i, 64);
                ra[i] = X4[(size_t)s * 8 + fl];
            }
        }
        __builtin_amdgcn_sched_barrier(0);
#pragma unroll
        for (int i = 0; i < 4; ++i) {
            f8 x = h16_to_f8(rb[i]);
#pragma unroll
            for (int j = 0; j < 8; ++j) acc[j] += x.v[j];
        }
    }
}

// ---------------- propagate + bias + BN-stats (fp16 in, fp16 out) ----------
// X4 rows are pre-scaled by dinv[src]; out = dinv[dst]*sum + bias.
__global__ __launch_bounds__(256, 3) void prop_stats_k(
        const float4* __restrict__ X4, const int* __restrict__ offs,
        const int* __restrict__ edge1, const float* __restrict__ dinv,
        const float* __restrict__ bias, const int* __restrict__ perm,
        float4* __restrict__ Y4, float* __restrict__ stats) {
    const int lane = threadIdx.x & 63;
    const int wave = threadIdx.x >> 6;
    const int slot = lane >> 3;
    const int fl = lane & 7;
    const int slotbase = lane & 56;
    const int wid = blockIdx.x * 4 + wave;
    const int nw = gridDim.x * 4;

    float bias8[8];
    {
        float4 b0 = ((const float4*)bias)[fl * 2];
        float4 b1 = ((const float4*)bias)[fl * 2 + 1];
        bias8[0] = b0.x; bias8[1] = b0.y; bias8[2] = b0.z; bias8[3] = b0.w;
        bias8[4] = b1.x; bias8[5] = b1.y; bias8[6] = b1.z; bias8[7] = b1.w;
    }

    float s1[8], s2[8];
#pragma unroll
    for (int j = 0; j < 8; ++j) { s1[j] = 0.f; s2[j] = 0.f; }

    for (int g = wid; g < NGRP; g += nw) {
        int n = perm[g * 8 + slot];
        float dn = dinv[n];
        f8 self = h16_to_f8(X4[(size_t)n * 8 + fl]);   // already dinv[n]-scaled
        float acc[8];
#pragma unroll
        for (int j = 0; j < 8; ++j) acc[j] = self.v[j];
        int e0 = offs[n], e1 = offs[n + 1];
        prop_gather8(X4, edge1, e0, e1, fl, slotbase, acc);
        f8 o;
#pragma unroll
        for (int j = 0; j < 8; ++j) {
            float a = fmaf(dn, acc[j], bias8[j]);
            o.v[j] = a;
            s1[j] += a;
            s2[j] = fmaf(a, a, s2[j]);
        }
        Y4[(size_t)n * 8 + fl] = f8_to_h16(o);
    }

    // reduce across the 8 slots (lanes differing in bits 3,4,5)
#pragma unroll
    for (int m = 8; m <= 32; m <<= 1) {
#pragma unroll
        for (int j = 0; j < 8; ++j) {
            s1[j] += __shfl_xor(s1[j], m, 64);
            s2[j] += __shfl_xor(s2[j], m, 64);
        }
    }

    __shared__ float red[4][8][16];
    if (lane < 8) {
#pragma unroll
        for (int j = 0; j < 8; ++j) {
            red[wave][lane][j] = s1[j];
            red[wave][lane][8 + j] = s2[j];
        }
    }
    __syncthreads();
    int t = threadIdx.x;
    if (t < 128) {
        int j = t & 63;            // feature index
        int isq = t >> 6;          // 0 = sum, 1 = sumsq
        int fli = j >> 3, c = (j & 7) + isq * 8;
        float a = red[0][fli][c] + red[1][fli][c] + red[2][fli][c] + red[3][fli][c];
        atomicAdd(&stats[(blockIdx.x & (NSLICE - 1)) * 128 + isq * 64 + j], a);
    }
}

// ------- batchnorm + relu (layer 4 only): fp16 in -> fp16 out + fp8 emit ---
__global__ __launch_bounds__(256) void bn_relu_k(
        const float4* __restrict__ Y4, const float* __restrict__ slices,
        const float* __restrict__ g, const float* __restrict__ be,
        float4* __restrict__ H4, uint2* __restrict__ X8,
        const float* __restrict__ dinv) {
    __shared__ float fs[128];
    int t = threadIdx.x;
    if (t < 128) {
        float s = 0.f;
#pragma unroll
        for (int k = 0; k < NSLICE; ++k) s += slices[k * 128 + t];
        fs[t] = s;
    }
    __syncthreads();
    int i = blockIdx.x * blockDim.x + t;
    if (i >= NN * 8) return;
    int fg = i & 7;                 // feats [fg*8, fg*8+8)
    const float invN = 1.f / (float)NN;
    f8 y = h16_to_f8(Y4[i]);
    float4 gv0 = ((const float4*)g)[fg * 2];
    float4 gv1 = ((const float4*)g)[fg * 2 + 1];
    float4 bv0 = ((const float4*)be)[fg * 2];
    float4 bv1 = ((const float4*)be)[fg * 2 + 1];
    float gv[8] = { gv0.x, gv0.y, gv0.z, gv0.w, gv1.x, gv1.y, gv1.z, gv1.w };
    float bv[8] = { bv0.x, bv0.y, bv0.z, bv0.w, bv1.x, bv1.y, bv1.z, bv1.w };
    f8 o;
#pragma unroll
    for (int j = 0; j < 8; ++j) {
        float m = fs[fg * 8 + j] * invN;
        float v = fs[64 + fg * 8 + j] * invN - m * m;
        float val = fmaf(gv[j] * rsqrtf(v + BN_EPS), y.v[j] - m, bv[j]);
        o.v[j] = val > 0.f ? val : 0.f;
    }
    H4[i] = f8_to_h16(o);
    {
        float dn = dinv[i >> 3];
        float sv[8];
#pragma unroll
        for (int j = 0; j < 8; ++j) sv[j] = dn * o.v[j];
        X8[i] = f_to_fp8x8(sv);
    }
}

// ---- fp8 APPNP: 16 nodes/wave, weight-free, 4+4 ping-pong (low-VGPR) ------
template <bool OUT16>
__global__ __launch_bounds__(256, 3) void appnp8_k(
        const uint4* __restrict__ X8, const float4* __restrict__ H04,
        const int* __restrict__ offs, const int* __restrict__ edge1,
        const float* __restrict__ dinv, const int* __restrict__ perm,
        uint4* __restrict__ Y8, float4* __restrict__ Y16) {
    const int lane = threadIdx.x & 63;
    const int wave = threadIdx.x >> 6;
    const int slot = lane >> 2;
    const int fl = lane & 3;
    const int quadbase = lane & 60;
    const int wid = blockIdx.x * 4 + wave;
    if (wid >= NG16) return;
    int n = perm[wid * 16 + slot];
    float dn = dinv[n];
    float acc[16];
    {
        float self[16];
        fp8x16_to_f(X8[(size_t)n * 4 + fl], self);   // already dinv[n]-scaled
#pragma unroll
        for (int j = 0; j < 16; ++j) acc[j] = self[j];
    }
    int e0 = offs[n], e1 = offs[n + 1];
    if (e0 < e1) {
        int2 d = ((const int2*)(edge1 + e0))[fl];   // 8 edges per slot group
        uint4 ra[4];
#pragma unroll
        for (int k = 0; k < 4; ++k) {
            int s = __shfl((k & 1) ? d.y : d.x, quadbase + (k >> 1), 64);
            ra[k] = X8[(size_t)s * 4 + fl];
        }
        for (int e = e0; e < e1; e += 8) {
            uint4 rb[4];
#pragma unroll
            for (int k = 0; k < 4; ++k) {
                int s = __shfl((k & 1) ? d.y : d.x, quadbase + 2 + (k >> 1), 64);
                rb[k] = X8[(size_t)s * 4 + fl];
            }
            bool more = (e + 8 < e1);
            if (more) d = ((const int2*)(edge1 + e + 8))[fl];
            __builtin_amdgcn_sched_barrier(0);
#pragma unroll
            for (int k = 0; k < 4; ++k) {
                float x[16];
                fp8x16_to_f(ra[k], x);
#pragma unroll
                for (int j = 0; j < 16; ++j) acc[j] += x[j];
            }
            if (more) {
#pragma unroll
                for (int k = 0; k < 4; ++k) {
                    int s = __shfl((k & 1) ? d.y : d.x, quadbase + (k >> 1), 64);
                    ra[k] = X8[(size_t)s * 4 + fl];
                }
            }
            __builtin_amdgcn_sched_barrier(0);
#pragma unroll
            for (int k = 0; k < 4; ++k) {
                float x[16];
                fp8x16_to_f(rb[k], x);
#pragma unroll
                for (int j = 0; j < 16; ++j) acc[j] += x[j];
            }
        }
    }
    // teleport: h0 fp16, feats [fl*16, fl*16+16) = float4 slots fl*2, fl*2+1
    f8 ha = h16_to_f8(H04[(size_t)n * 8 + fl * 2]);
    f8 hb = h16_to_f8(H04[(size_t)n * 8 + fl * 2 + 1]);
    float o[16];
    float s = 0.9f * dn;
#pragma unroll
    for (int j = 0; j < 8; ++j) {
        o[j] = fmaf(s, acc[j], 0.1f * ha.v[j]);
        o[8 + j] = fmaf(s, acc[8 + j], 0.1f * hb.v[j]);
    }
    if (OUT16) {
        f8 lo, hi;
#pragma unroll
        for (int j = 0; j < 8; ++j) { lo.v[j] = o[j]; hi.v[j] = o[8 + j]; }
        Y16[(size_t)n * 8 + fl * 2] = f8_to_h16(lo);
        Y16[(size_t)n * 8 + fl * 2 + 1] = f8_to_h16(hi);
    } else {
        float so[16];
#pragma unroll
        for (int j = 0; j < 16; ++j) so[j] = dn * o[j];
        Y8[(size_t)n * 4 + fl] = f_to_fp8x16(so);
    }
}

// ---------------- FC + log_softmax (fp16 in, fp32 out) ----------------
__global__ __launch_bounds__(256) void final_k(const float2* __restrict__ H2,
                                               const float* __restrict__ Wfc,
                                               const float* __restrict__ bfc,
                                               float* __restrict__ out) {
    const int t = threadIdx.x;
    const int n0 = blockIdx.x * 64;
    const int r0 = (t >> 4) << 2;
    const int c0 = (t & 15) << 2;

    int r[4];
#pragma unroll
    for (int j = 0; j < 4; ++j) {
        int rr = n0 + r0 + j;
        r[j] = rr < NN ? rr : NN - 1;
    }
    const float2* Xr[4];
#pragma unroll
    for (int j = 0; j < 4; ++j) Xr[j] = H2 + (size_t)r[j] * 16;

    float4 bf = *(const float4*)(bfc + c0);
    float acc[4][4];
#pragma unroll
    for (int j = 0; j < 4; ++j) {
        acc[j][0] = bf.x; acc[j][1] = bf.y; acc[j][2] = bf.z; acc[j][3] = bf.w;
    }

#pragma unroll 4
    for (int kq = 0; kq < 16; ++kq) {
        float4 xv[4];
#pragma unroll
        for (int j = 0; j < 4; ++j) xv[j] = h8_to_f4(Xr[j][kq]);
        float4 wv[4];
#pragma unroll
        for (int i = 0; i < 4; ++i)
            wv[i] = *(const float4*)(Wfc + (size_t)(kq * 4 + i) * 64 + c0);
#pragma unroll
        for (int j = 0; j < 4; ++j) {
            acc[j][0] = fmaf(xv[j].x, wv[0].x, acc[j][0]);
            acc[j][1] = fmaf(xv[j].x, wv[0].y, acc[j][1]);
            acc[j][2] = fmaf(xv[j].x, wv[0].z, acc[j][2]);
            acc[j][3] = fmaf(xv[j].x, wv[0].w, acc[j][3]);
            acc[j][0] = fmaf(xv[j].y, wv[1].x, acc[j][0]);
            acc[j][1] = fmaf(xv[j].y, wv[1].y, acc[j][1]);
            acc[j][2] = fmaf(xv[j].y, wv[1].z, acc[j][2]);
            acc[j][3] = fmaf(xv[j].y, wv[1].w, acc[j][3]);
            acc[j][0] = fmaf(xv[j].z, wv[2].x, acc[j][0]);
            acc[j][1] = fmaf(xv[j].z, wv[2].y, acc[j][1]);
            acc[j][2] = fmaf(xv[j].z, wv[2].z, acc[j][2]);
            acc[j][3] = fmaf(xv[j].z, wv[2].w, acc[j][3]);
            acc[j][0] = fmaf(xv[j].w, wv[3].x, acc[j][0]);
            acc[j][1] = fmaf(xv[j].w, wv[3].y, acc[j][1]);
            acc[j][2] = fmaf(xv[j].w, wv[3].z, acc[j][2]);
            acc[j][3] = fmaf(xv[j].w, wv[3].w, acc[j][3]);
        }
    }

#pragma unroll
    for (int j = 0; j < 4; ++j) {
        float m = fmaxf(fmaxf(acc[j][0], acc[j][1]), fmaxf(acc[j][2], acc[j][3]));
#pragma unroll
        for (int d = 1; d <= 8; d <<= 1) m = fmaxf(m, __shfl_xor(m, d, 64));
        float s = expf(acc[j][0] - m) + expf(acc[j][1] - m) +
                  expf(acc[j][2] - m) + expf(acc[j][3] - m);
#pragma unroll
        for (int d = 1; d <= 8; d <<= 1) s += __shfl_xor(s, d, 64);
        float lse = m + logf(s);
        int rr = n0 + r0 + j;
        if (rr < NN)
            *(float4*)(out + (size_t)rr * 64 + c0) =
                make_float4(acc[j][0] - lse, acc[j][1] - lse,
                            acc[j][2] - lse, acc[j][3] - lse);
    }
}

// ---------------- host launch ----------------

static inline char* alignup(char* p, size_t a) {
    return (char*)(((uintptr_t)p + a - 1) & ~(uintptr_t)(a - 1));
}

extern "C" void kernel_launch(void* const* d_in, const int* in_sizes, int n_in,
                              void* d_out, int out_size, void* d_ws, size_t ws_size,
                              hipStream_t stream) {
    const float* x   = (const float*)d_in[0];
    const int*   ei  = (const int*)d_in[1];
    const float* W1  = (const float*)d_in[2];
    const float* b1  = (const float*)d_in[3];
    const float* W2  = (const float*)d_in[4];
    const float* b2  = (const float*)d_in[5];
    const float* Wx  = (const float*)d_in[6];
    const float* bx  = (const float*)d_in[7];
    const float* g1  = (const float*)d_in[8];
    const float* be1 = (const float*)d_in[9];
    const float* g2  = (const float*)d_in[10];
    const float* be2 = (const float*)d_in[11];
    const float* g3  = (const float*)d_in[12];
    const float* be3 = (const float*)d_in[13];
    const float* Wfc = (const float*)d_in[14];
    const float* bfc = (const float*)d_in[15];
    float* out = (float*)d_out;

    const int* srcA = ei;
    const int* dstA = ei + NE;

    char* p = (char*)d_ws;
    int*   deg    = (int*)p;   p += NN * 4;
    float* stats  = (float*)p; p += 4 * NSLICE * 128 * 4;   // 4 layers x 32 slices x 128
    int*   hist   = (int*)p;   p += NBKT * 4;               // zeroed each launch
    size_t zbytes = (size_t)(p - (char*)d_ws);
    p = alignup(p, 512);
    int*   offs  = (int*)p;    p += (NN + 4) * 4;   p = alignup(p, 512);
    float* dinv  = (float*)p;  p += NN * 4;         p = alignup(p, 512);
    int*   bsum  = (int*)p;    p += 256 * 4;
    int*   bpre  = (int*)p;    p += 256 * 4;
    int*   bcur  = (int*)p;    p += NBKT * 4;
    int*   bincnt = (int*)p;   p += 256 * 4;
    int*   bbcur  = (int*)p;   p += 256 * 4;
    int*   boffs  = (int*)p;   p += 260 * 4;        p = alignup(p, 512);
    int*   perm  = (int*)p;    p += NN * 4;         p = alignup(p, 512);
    int*   edge1 = (int*)p;    p += ((size_t)NE + 8 * NN + 256) * 4; p = alignup(p, 512);
    int2*  pairs = (int2*)p;   p += (size_t)NE * 8; p = alignup(p, 512);
    float4* tmpH = (float4*)p; p += ((size_t)NN + 1) * 128; p = alignup(p, 512);
    float4* hbH  = (float4*)p; p += (size_t)NN * 128;       p = alignup(p, 512);
    float4* apH  = (float4*)p; p += (size_t)NN * 128;       p = alignup(p, 512);
    float4* pbH  = (float4*)p; p += (size_t)NN * 128;       p = alignup(p, 512);
    uint4*  x8a  = (uint4*)p;  p += ((size_t)NN + 1) * 64;  p = alignup(p, 512);
    uint4*  x8b  = (uint4*)p;  p += ((size_t)NN + 1) * 64;

    hipMemsetAsync(d_ws, 0, zbytes, stream);

    count_k<<<(NE + 255) / 256, 256, 0, stream>>>(dstA, deg);
    dinv_k<<<(NN + 255) / 256, 256, 0, stream>>>(deg, dinv);
    zrow_k<<<1, 64, 0, stream>>>(tmpH, x8a, x8b);
    hist_k<<<SCAN_B, 256, 0, stream>>>(deg, hist);
    scan16_k<<<1, 64, 0, stream>>>(hist, bcur);
    perm_k<<<SCAN_B, 256, 0, stream>>>(deg, bcur, perm);
    scan1_k<<<SCAN_B, 256, 0, stream>>>(deg, offs, bsum);
    scan2_k<<<1, 256, 0, stream>>>(bsum, bpre, offs);
    scan3_k<<<(NN + 255) / 256, 256, 0, stream>>>(offs, bpre);
    pad_k<<<(NN + 255) / 256, 256, 0, stream>>>(deg, offs, edge1);
    // binned scatter replaces the random-write scatter_k
    binhist_k<<<NBIN, 256, 0, stream>>>(deg, bincnt);
    scanbin_k<<<1, 256, 0, stream>>>(bincnt, boffs, bbcur);
    binscat_k<<<(NE + EPB - 1) / EPB, 256, 0, stream>>>(srcA, dstA, bbcur, pairs);
    binplace_k<<<NBIN, 256, 0, stream>>>(boffs, pairs, offs, edge1);

    const int MMG = (NN + 63) / 64;          // 782
    const int PG  = (NGRP + 3) / 4;          // 1563: one octet per wave
    const int AG  = (NG16 + 3) / 4;          // 782:  one 16-group per wave
    const int BNG = (NN * 8 + 255) / 256;    // 1563
    const int SL  = NSLICE * 128;            // floats per layer slice block

    // L1: mm -> prop(stats0)
    mm_k<INF_, false><<<MMG, 256, 0, stream>>>(x, W1, dinv, (float2*)tmpH);
    prop_stats_k<<<PG, 256, 0, stream>>>(tmpH, offs, edge1, dinv, b1, perm, pbH, stats + 0 * SL);
    // L2: BN(stats0,g1,be1) fused into mm(W2) -> prop(stats1)
    mm_bn_k<<<MMG, 256, 0, stream>>>(pbH, stats + 0 * SL, g1, be1, W2, dinv, (float2*)tmpH);
    prop_stats_k<<<PG, 256, 0, stream>>>(tmpH, offs, edge1, dinv, b2, perm, pbH, stats + 1 * SL);
    // L3: BN(stats1,g2,be2) fused into mm(Wx0) -> prop(stats2)
    mm_bn_k<<<MMG, 256, 0, stream>>>(pbH, stats + 1 * SL, g2, be2, Wx, dinv, (float2*)tmpH);
    prop_stats_k<<<PG, 256, 0, stream>>>(tmpH, offs, edge1, dinv, bx, perm, pbH, stats + 2 * SL);
    // L4: BN(stats2,g3,be3) fused into mm(Wx1) -> prop(stats3)
    mm_bn_k<<<MMG, 256, 0, stream>>>(pbH, stats + 2 * SL, g3, be3,
                                     Wx + (size_t)64 * 64, dinv, (float2*)tmpH);
    prop_stats_k<<<PG, 256, 0, stream>>>(tmpH, offs, edge1, dinv, bx + 64, perm,
                                         pbH, stats + 3 * SL);
    // final BN -> H0 (fp16) + fp8 seed
    bn_relu_k<<<BNG, 256, 0, stream>>>(pbH, stats + 3 * SL, g3, be3, hbH, (uint2*)x8a, dinv);

    // APPNP in fp8: 9 fp8->fp8 iters ping-pong; 10th -> fp16 apH
    const uint4* cur8 = x8a;
    for (int it = 0; it < 9; ++it) {
        uint4* o8 = (cur8 == x8a) ? x8b : x8a;
        appnp8_k<false><<<AG, 256, 0, stream>>>(cur8, hbH, offs, edge1, dinv, perm, o8, nullptr);
        cur8 = o8;
    }
    appnp8_k<true><<<AG, 256, 0, stream>>>(cur8, hbH, offs, edge1, dinv, perm, nullptr, apH);

    final_k<<<MMG, 256, 0, stream>>>((const float2*)apH, Wfc, bfc, out);
}

// Round 12
// 426.124 us; speedup vs baseline: 4.3535x; 1.1179x over previous
//
#include <hip/hip_runtime.h>
#include <hip/hip_fp16.h>
#include <cstdint>
#include <cstddef>

#define NN 50000
#define NE 800000
#define HID 64
#define INF_ 128
#define BN_EPS 1e-5f
#define NGRP (NN / 8)        // 6250 node-octets for fp16 props
#define NG16 (NN / 16)       // 3125 node-16-groups for fp8 APPNP
#define SCAN_B 196           // ceil(50000/256)
#define NSLICE 32            // stats partial slices (contention fix)
#define NBKT 16              // degree buckets (chunk count = ceil(deg/8), capped)
#define NBIN 196             // dst bins of 256 nodes
#define EPB 2048             // edges per binscat block
#define BCAP 5120            // bin capacity: mean 4096 + 16 sigma (64)

typedef float floatx2 __attribute__((ext_vector_type(2)));

// ---------------- fp16 pack/unpack ----------------
__device__ __forceinline__ float4 h8_to_f4(float2 raw) {
    union { float f; __half2 h; } ua, ub;
    ua.f = raw.x; ub.f = raw.y;
    float2 fa = __half22float2(ua.h), fb = __half22float2(ub.h);
    return make_float4(fa.x, fa.y, fb.x, fb.y);
}
__device__ __forceinline__ float2 f4_to_h8(float4 v) {
    union { float f; __half2 h; } ua, ub;
    ua.h = __float22half2_rn(make_float2(v.x, v.y));
    ub.h = __float22half2_rn(make_float2(v.z, v.w));
    return make_float2(ua.f, ub.f);
}
struct f8 { float v[8]; };
__device__ __forceinline__ f8 h16_to_f8(float4 raw) {
    f8 r;
    union { float f; __half2 h; } u;
    float2 a;
    u.f = raw.x; a = __half22float2(u.h); r.v[0] = a.x; r.v[1] = a.y;
    u.f = raw.y; a = __half22float2(u.h); r.v[2] = a.x; r.v[3] = a.y;
    u.f = raw.z; a = __half22float2(u.h); r.v[4] = a.x; r.v[5] = a.y;
    u.f = raw.w; a = __half22float2(u.h); r.v[6] = a.x; r.v[7] = a.y;
    return r;
}
__device__ __forceinline__ float4 f8_to_h16(const f8& s) {
    union { float f; __half2 h; } u;
    float4 o;
    u.h = __float22half2_rn(make_float2(s.v[0], s.v[1])); o.x = u.f;
    u.h = __float22half2_rn(make_float2(s.v[2], s.v[3])); o.y = u.f;
    u.h = __float22half2_rn(make_float2(s.v[4], s.v[5])); o.z = u.f;
    u.h = __float22half2_rn(make_float2(s.v[6], s.v[7])); o.w = u.f;
    return o;
}

// ---------------- fp8 e4m3 (OCP, gfx950 HW cvt) pack/unpack ----------------
__device__ __forceinline__ void fp8x8_to_f(unsigned lo, unsigned hi, float out[8]) {
    floatx2 a = __builtin_amdgcn_cvt_pk_f32_fp8((int)lo, false);
    floatx2 b = __builtin_amdgcn_cvt_pk_f32_fp8((int)lo, true);
    floatx2 c = __builtin_amdgcn_cvt_pk_f32_fp8((int)hi, false);
    floatx2 d = __builtin_amdgcn_cvt_pk_f32_fp8((int)hi, true);
    out[0] = a[0]; out[1] = a[1]; out[2] = b[0]; out[3] = b[1];
    out[4] = c[0]; out[5] = c[1]; out[6] = d[0]; out[7] = d[1];
}
__device__ __forceinline__ void fp8x16_to_f(uint4 r, float out[16]) {
    fp8x8_to_f(r.x, r.y, out);
    fp8x8_to_f(r.z, r.w, out + 8);
}
__device__ __forceinline__ uint2 f_to_fp8x8(const float v[8]) {
    int w0 = __builtin_amdgcn_cvt_pk_fp8_f32(v[0], v[1], 0, false);
    w0 = __builtin_amdgcn_cvt_pk_fp8_f32(v[2], v[3], w0, true);
    int w1 = __builtin_amdgcn_cvt_pk_fp8_f32(v[4], v[5], 0, false);
    w1 = __builtin_amdgcn_cvt_pk_fp8_f32(v[6], v[7], w1, true);
    uint2 o; o.x = (unsigned)w0; o.y = (unsigned)w1;
    return o;
}
__device__ __forceinline__ uint4 f_to_fp8x16(const float v[16]) {
    uint2 a = f_to_fp8x8(v), b = f_to_fp8x8(v + 8);
    uint4 o; o.x = a.x; o.y = a.y; o.z = b.x; o.w = b.y;
    return o;
}

// ---------------- graph prep ----------------

// pass A (FIRST kernel): LDS bucket sort of EPB edges into NBIN dst-bins,
// dynamic per-bin global cursors (196-way contention only), fixed-capacity
// bin regions (b*BCAP). Replaces count_k+binhist+scanbin ordering needs.
__global__ __launch_bounds__(256) void binscat_k(
        const int* __restrict__ src, const int* __restrict__ dst,
        int* __restrict__ bcur, int2* __restrict__ pairs) {
    __shared__ int lcnt[256], lscan[256], lexc[256], gbase[256];
    __shared__ int2 stage[EPB];
    const int t = threadIdx.x;
    const int base = blockIdx.x * EPB;
    lcnt[t] = 0;
    __syncthreads();
    int2 mypair[EPB / 256];
    int mybin[EPB / 256], myr[EPB / 256];
#pragma unroll
    for (int i = 0; i < EPB / 256; ++i) {
        int e = base + i * 256 + t;
        if (e < NE) {
            int s = src[e], d = dst[e];
            mypair[i] = make_int2(s, d);
            mybin[i] = d >> 8;
            myr[i] = atomicAdd(&lcnt[mybin[i]], 1);
        } else mybin[i] = -1;
    }
    __syncthreads();
    lscan[t] = lcnt[t];
    __syncthreads();
    for (int d = 1; d < 256; d <<= 1) {
        int u = (t >= d) ? lscan[t - d] : 0;
        __syncthreads();
        lscan[t] += u;
        __syncthreads();
    }
    lexc[t] = lscan[t] - lcnt[t];
    if (lcnt[t] > 0) gbase[t] = atomicAdd(&bcur[t], lcnt[t]);
    __syncthreads();
#pragma unroll
    for (int i = 0; i < EPB / 256; ++i)
        if (mybin[i] >= 0) stage[lexc[mybin[i]] + myr[i]] = mypair[i];
    __syncthreads();
    const int total = lscan[255];
#pragma unroll
    for (int i = 0; i < EPB / 256; ++i) {
        int s = i * 256 + t;
        if (s < total) {
            int2 pr = stage[s];
            int b = pr.y >> 8;
            pairs[(size_t)b * BCAP + gbase[b] + (s - lexc[b])] = pr;
        }
    }
}

// per-bin degree count from binned pairs (LDS atomics, L2-local reads);
// epilogue also emits dinv and the degree-bucket histogram (folds 3 kernels).
__global__ __launch_bounds__(256) void bincnt_k(
        const int2* __restrict__ pairs, const int* __restrict__ bcur,
        int* __restrict__ deg, float* __restrict__ dinv, int* __restrict__ hist) {
    __shared__ int lc[256];
    __shared__ int lh[NBKT];
    const int b = blockIdx.x, t = threadIdx.x;
    lc[t] = 0;
    if (t < NBKT) lh[t] = 0;
    __syncthreads();
    const int cnt = bcur[b];
    const size_t s0 = (size_t)b * BCAP;
    for (int s = t; s < cnt; s += 256)
        atomicAdd(&lc[pairs[s0 + s].y & 255], 1);
    __syncthreads();
    int n = b * 256 + t;
    if (n < NN) {
        int d = lc[t];
        deg[n] = d;
        dinv[n] = rsqrtf((float)(d + 1));        // +1 self-loop
        int c = (d + 7) >> 3;
        if (c > NBKT - 1) c = NBKT - 1;
        atomicAdd(&lh[c], 1);
    }
    __syncthreads();
    if (t < NBKT && lh[t]) atomicAdd(&hist[t], lh[t]);
}

// parallel scan of PADDED degrees ((deg+7)&~7) -> offs; 3 kernels
__global__ void scan1_k(const int* __restrict__ cnt, int* __restrict__ offs,
                        int* __restrict__ bsum) {
    __shared__ int sh[256];
    int t = threadIdx.x, i = blockIdx.x * 256 + t;
    int v = (i < NN) ? ((cnt[i] + 7) & ~7) : 0;
    sh[t] = v;
    __syncthreads();
    for (int d = 1; d < 256; d <<= 1) {
        int u = (t >= d) ? sh[t - d] : 0;
        __syncthreads();
        sh[t] += u;
        __syncthreads();
    }
    if (i < NN) offs[i] = sh[t] - v;
    if (t == 255) bsum[blockIdx.x] = sh[255];
}

__global__ void scan2_k(const int* __restrict__ bsum, int* __restrict__ bpre,
                        int* __restrict__ offs) {
    __shared__ int sh[256];
    int t = threadIdx.x;
    int v = (t < SCAN_B) ? bsum[t] : 0;
    sh[t] = v;
    __syncthreads();
    for (int d = 1; d < 256; d <<= 1) {
        int u = (t >= d) ? sh[t - d] : 0;
        __syncthreads();
        sh[t] += u;
        __syncthreads();
    }
    bpre[t] = sh[t] - v;
    if (t == 255) offs[NN] = sh[255];
}

__global__ void scan3_k(int* __restrict__ offs, const int* __restrict__ bpre) {
    int i = blockIdx.x * blockDim.x + threadIdx.x;
    if (i < NN) offs[i] += bpre[i >> 8];
}

// pad CSR tails with the all-zero row NN; block 0 also zeroes that row
__global__ void pad_k(const int* __restrict__ cnt, const int* __restrict__ offs,
                      int* __restrict__ edge1, float4* __restrict__ tmpH,
                      uint4* __restrict__ x8a, uint4* __restrict__ x8b) {
    int t = threadIdx.x;
    if (blockIdx.x == 0) {
        if (t < 8) tmpH[(size_t)NN * 8 + t] = make_float4(0.f, 0.f, 0.f, 0.f);
        else if (t < 12) x8a[(size_t)NN * 4 + (t - 8)] = make_uint4(0, 0, 0, 0);
        else if (t < 16) x8b[(size_t)NN * 4 + (t - 12)] = make_uint4(0, 0, 0, 0);
    }
    int n = blockIdx.x * blockDim.x + t;
    if (n >= NN) return;
    int e = offs[n] + cnt[n], e1 = offs[n + 1];
    for (; e < e1; ++e) edge1[e] = NN;
}

// pass B: one block per bin; place edges into CSR. Random writes confined to
// the bin's ~20KB CSR window -> L2-coalesced full lines to HBM.
__global__ __launch_bounds__(256) void binplace_k(
        const int* __restrict__ bcur, const int2* __restrict__ pairs,
        const int* __restrict__ offs, int* __restrict__ edge1) {
    __shared__ int lcur[256];
    const int b = blockIdx.x, t = threadIdx.x;
    lcur[t] = 0;
    __syncthreads();
    const int cnt = bcur[b];
    const size_t s0 = (size_t)b * BCAP;
    for (int s = t; s < cnt; s += 256) {
        int2 pr = pairs[s0 + s];
        int d = pr.y;
        int slot = atomicAdd(&lcur[d & 255], 1);
        edge1[offs[d] + slot] = pr.x;
    }
}

// ---- degree-bucketed node permutation ------------------------------------
__global__ void scan16_k(const int* __restrict__ hist, int* __restrict__ bcur) {
    if (threadIdx.x == 0) {
        int s = 0;
        for (int i = 0; i < NBKT; ++i) { bcur[i] = s; s += hist[i]; }
    }
}

__global__ void perm_k(const int* __restrict__ cnt, int* __restrict__ bcur,
                       int* __restrict__ perm) {
    __shared__ int lh[NBKT], lbase[NBKT];
    int t = threadIdx.x;
    if (t < NBKT) lh[t] = 0;
    __syncthreads();
    int n = blockIdx.x * 256 + t;
    int c = 0, r = 0;
    if (n < NN) {
        c = (cnt[n] + 7) >> 3;
        if (c > NBKT - 1) c = NBKT - 1;
        r = atomicAdd(&lh[c], 1);
    }
    __syncthreads();
    if (t < NBKT) lbase[t] = lh[t] ? atomicAdd(&bcur[t], lh[t]) : 0;
    __syncthreads();
    if (n < NN) perm[lbase[c] + r] = n;
}

// ------ dense matmul: Y[N,64] = dinv[n] * (X[N,K] @ W[K,64]), fp16 out -----
template <int K, bool HIN>
__global__ __launch_bounds__(256, 2) void mm_k(const void* __restrict__ Xv,
                                               const float* __restrict__ W,
                                               const float* __restrict__ dinv,
                                               float2* __restrict__ Y) {
    constexpr int RS = K + 4;            // LDS row stride (floats); keeps 16B align
    __shared__ float Xs[64 * RS];
    __shared__ float Ws[K * 64];
    const int t = threadIdx.x;
    const int n0 = blockIdx.x * 64;

    // stage W: K*16 float4, coalesced
    {
        const float4* Wg = (const float4*)W;
        for (int g2 = t; g2 < K * 16; g2 += 256) {
            int row = g2 >> 4, c4 = g2 & 15;
            *(float4*)&Ws[row * 64 + c4 * 4] = Wg[g2];
        }
    }
    // stage X tile (clamped rows for the tail block)
    if (HIN) {
        const float4* Xg = (const float4*)Xv;      // 8 halves per float4
        for (int g2 = t; g2 < 64 * (K / 8); g2 += 256) {
            int row = g2 / (K / 8), c8 = g2 % (K / 8);
            int rr = n0 + row; if (rr >= NN) rr = NN - 1;
            f8 v = h16_to_f8(Xg[(size_t)rr * (K / 8) + c8]);
            float* dp = &Xs[row * RS + c8 * 8];
#pragma unroll
            for (int j = 0; j < 8; ++j) dp[j] = v.v[j];
        }
    } else {
        const float4* Xg = (const float4*)Xv;
        for (int g2 = t; g2 < 64 * (K / 4); g2 += 256) {
            int row = g2 / (K / 4), c4 = g2 % (K / 4);
            int rr = n0 + row; if (rr >= NN) rr = NN - 1;
            *(float4*)&Xs[row * RS + c4 * 4] = Xg[(size_t)rr * (K / 4) + c4];
        }
    }
    __syncthreads();

    const int r0 = (t >> 4) << 2;
    const int c0 = (t & 15) << 2;
    float acc[4][4];
#pragma unroll
    for (int j = 0; j < 4; ++j)
#pragma unroll
        for (int c = 0; c < 4; ++c) acc[j][c] = 0.f;

#pragma unroll 8
    for (int kq = 0; kq < K / 4; ++kq) {
        float4 xv[4];
#pragma unroll
        for (int j = 0; j < 4; ++j)
            xv[j] = *(const float4*)&Xs[(r0 + j) * RS + kq * 4];
        float4 wv[4];
#pragma unroll
        for (int i = 0; i < 4; ++i)
            wv[i] = *(const float4*)&Ws[(kq * 4 + i) * 64 + c0];
#pragma unroll
        for (int j = 0; j < 4; ++j) {
            acc[j][0] = fmaf(xv[j].x, wv[0].x, acc[j][0]);
            acc[j][1] = fmaf(xv[j].x, wv[0].y, acc[j][1]);
            acc[j][2] = fmaf(xv[j].x, wv[0].z, acc[j][2]);
            acc[j][3] = fmaf(xv[j].x, wv[0].w, acc[j][3]);
            acc[j][0] = fmaf(xv[j].y, wv[1].x, acc[j][0]);
            acc[j][1] = fmaf(xv[j].y, wv[1].y, acc[j][1]);
            acc[j][2] = fmaf(xv[j].y, wv[1].z, acc[j][2]);
            acc[j][3] = fmaf(xv[j].y, wv[1].w, acc[j][3]);
            acc[j][0] = fmaf(xv[j].z, wv[2].x, acc[j][0]);
            acc[j][1] = fmaf(xv[j].z, wv[2].y, acc[j][1]);
            acc[j][2] = fmaf(xv[j].z, wv[2].z, acc[j][2]);
            acc[j][3] = fmaf(xv[j].z, wv[2].w, acc[j][3]);
            acc[j][0] = fmaf(xv[j].w, wv[3].x, acc[j][0]);
            acc[j][1] = fmaf(xv[j].w, wv[3].y, acc[j][1]);
            acc[j][2] = fmaf(xv[j].w, wv[3].z, acc[j][2]);
            acc[j][3] = fmaf(xv[j].w, wv[3].w, acc[j][3]);
        }
    }

#pragma unroll
    for (int j = 0; j < 4; ++j) {
        int rr = n0 + r0 + j;
        if (rr < NN) {
            float dn = dinv[rr];
            Y[(size_t)rr * 16 + (t & 15)] =
                f4_to_h8(make_float4(acc[j][0] * dn, acc[j][1] * dn,
                                     acc[j][2] * dn, acc[j][3] * dn));
        }
    }
}

// ---- fused BN+ReLU -> matmul (K=64): replaces 3 bn_relu passes ------------
__global__ __launch_bounds__(256, 2) void mm_bn_k(
        const float4* __restrict__ Y4in, const float* __restrict__ slices,
        const float* __restrict__ gg, const float* __restrict__ be,
        const float* __restrict__ W, const float* __restrict__ dinv,
        float2* __restrict__ Y) {
    constexpr int K = 64, RS = K + 4;
    __shared__ float Xs[64 * RS];
    __shared__ float Ws[K * 64];
    __shared__ float fs[128], gs[64], bs[64];
    const int t = threadIdx.x;
    const int n0 = blockIdx.x * 64;

    if (t < 128) {
        float s = 0.f;
#pragma unroll
        for (int k = 0; k < NSLICE; ++k) s += slices[k * 128 + t];
        fs[t] = s;
    } else if (t < 192) {
        gs[t - 128] = gg[t - 128];
    } else {
        bs[t - 192] = be[t - 192];
    }
    {
        const float4* Wg = (const float4*)W;
        for (int g2 = t; g2 < K * 16; g2 += 256) {
            int row = g2 >> 4, c4 = g2 & 15;
            *(float4*)&Ws[row * 64 + c4 * 4] = Wg[g2];
        }
    }
    __syncthreads();

    const float invN = 1.f / (float)NN;
    for (int g2 = t; g2 < 64 * 8; g2 += 256) {
        int row = g2 >> 3, c8 = g2 & 7;
        int rr = n0 + row; if (rr >= NN) rr = NN - 1;
        f8 v = h16_to_f8(Y4in[(size_t)rr * 8 + c8]);
        float* dp = &Xs[row * RS + c8 * 8];
#pragma unroll
        for (int j = 0; j < 8; ++j) {
            int f = c8 * 8 + j;
            float m = fs[f] * invN;
            float va = fs[64 + f] * invN - m * m;
            float val = fmaf(gs[f] * rsqrtf(va + BN_EPS), v.v[j] - m, bs[f]);
            dp[j] = val > 0.f ? val : 0.f;
        }
    }
    __syncthreads();

    const int r0 = (t >> 4) << 2;
    const int c0 = (t & 15) << 2;
    float acc[4][4];
#pragma unroll
    for (int j = 0; j < 4; ++j)
#pragma unroll
        for (int c = 0; c < 4; ++c) acc[j][c] = 0.f;

#pragma unroll 8
    for (int kq = 0; kq < K / 4; ++kq) {
        float4 xv[4];
#pragma unroll
        for (int j = 0; j < 4; ++j)
            xv[j] = *(const float4*)&Xs[(r0 + j) * RS + kq * 4];
        float4 wv[4];
#pragma unroll
        for (int i = 0; i < 4; ++i)
            wv[i] = *(const float4*)&Ws[(kq * 4 + i) * 64 + c0];
#pragma unroll
        for (int j = 0; j < 4; ++j) {
            acc[j][0] = fmaf(xv[j].x, wv[0].x, acc[j][0]);
            acc[j][1] = fmaf(xv[j].x, wv[0].y, acc[j][1]);
            acc[j][2] = fmaf(xv[j].x, wv[0].z, acc[j][2]);
            acc[j][3] = fmaf(xv[j].x, wv[0].w, acc[j][3]);
            acc[j][0] = fmaf(xv[j].y, wv[1].x, acc[j][0]);
            acc[j][1] = fmaf(xv[j].y, wv[1].y, acc[j][1]);
            acc[j][2] = fmaf(xv[j].y, wv[1].z, acc[j][2]);
            acc[j][3] = fmaf(xv[j].y, wv[1].w, acc[j][3]);
            acc[j][0] = fmaf(xv[j].z, wv[2].x, acc[j][0]);
            acc[j][1] = fmaf(xv[j].z, wv[2].y, acc[j][1]);
            acc[j][2] = fmaf(xv[j].z, wv[2].z, acc[j][2]);
            acc[j][3] = fmaf(xv[j].z, wv[2].w, acc[j][3]);
            acc[j][0] = fmaf(xv[j].w, wv[3].x, acc[j][0]);
            acc[j][1] = fmaf(xv[j].w, wv[3].y, acc[j][1]);
            acc[j][2] = fmaf(xv[j].w, wv[3].z, acc[j][2]);
            acc[j][3] = fmaf(xv[j].w, wv[3].w, acc[j][3]);
        }
    }

#pragma unroll
    for (int j = 0; j < 4; ++j) {
        int rr = n0 + r0 + j;
        if (rr < NN) {
            float dn = dinv[rr];
            Y[(size_t)rr * 16 + (t & 15)] =
                f4_to_h8(make_float4(acc[j][0] * dn, acc[j][1] * dn,
                                     acc[j][2] * dn, acc[j][3] * dn));
        }
    }
}

// ---- fp16 propagate core: weight-free, 4+4 ping-pong (low-VGPR) -----------
__device__ __forceinline__ void prop_gather8(const float4* __restrict__ X4,
                                             const int* __restrict__ E,
                                             int e0, int e1, int fl, int slotbase,
                                             float acc[8]) {
    if (e0 >= e1) return;
    int d = E[e0 + fl];                 // 8 edge idxs for this slot group
    float4 ra[4];
#pragma unroll
    for (int i = 0; i < 4; ++i) {
        int s = __shfl(d, slotbase + i, 64);
        ra[i] = X4[(size_t)s * 8 + fl];
    }
    for (int e = e0; e < e1; e += 8) {
        float4 rb[4];
#pragma unroll
        for (int i = 0; i < 4; ++i) {
            int s = __shfl(d, slotbase + 4 + i, 64);
            rb[i] = X4[(size_t)s * 8 + fl];
        }
        bool more = (e + 8 < e1);
        if (more) d = E[e + 8 + fl];    // prefetch next block's indices
        __builtin_amdgcn_sched_barrier(0);
#pragma unroll
        for (int i = 0; i < 4; ++i) {
            f8 x = h16_to_f8(ra[i]);
#pragma unroll
            for (int j = 0; j < 8; ++j) acc[j] += x.v[j];
        }
        if (more) {
#pragma unroll
            for (int i = 0; i < 4; ++i) {
                int s = __shfl(d, slotbase + i, 64);
                ra[i] = X4[(size_t)s * 8 + fl];
            }
        }
        __builtin_amdgcn_sched_barrier(0);
#pragma unroll
        for (int i = 0; i < 4; ++i) {
            f8 x = h16_to_f8(rb[i]);
#pragma unroll
            for (int j = 0; j < 8; ++j) acc[j] += x.v[j];
        }
    }
}

// ---------------- propagate + bias + BN-stats (fp16 in, fp16 out) ----------
__global__ __launch_bounds__(256, 3) void prop_stats_k(
        const float4* __restrict__ X4, const int* __restrict__ offs,
        const int* __restrict__ edge1, const float* __restrict__ dinv,
        const float* __restrict__ bias, const int* __restrict__ perm,
        float4* __restrict__ Y4, float* __restrict__ stats) {
    const int lane = threadIdx.x & 63;
    const int wave = threadIdx.x >> 6;
    const int slot = lane >> 3;
    const int fl = lane & 7;
    const int slotbase = lane & 56;
    const int wid = blockIdx.x * 4 + wave;
    const int nw = gridDim.x * 4;

    float bias8[8];
    {
        float4 b0 = ((const float4*)bias)[fl * 2];
        float4 b1 = ((const float4*)bias)[fl * 2 + 1];
        bias8[0] = b0.x; bias8[1] = b0.y; bias8[2] = b0.z; bias8[3] = b0.w;
        bias8[4] = b1.x; bias8[5] = b1.y; bias8[6] = b1.z; bias8[7] = b1.w;
    }

    float s1[8], s2[8];
#pragma unroll
    for (int j = 0; j < 8; ++j) { s1[j] = 0.f; s2[j] = 0.f; }

    for (int g = wid; g < NGRP; g += nw) {
        int n = perm[g * 8 + slot];
        float dn = dinv[n];
        f8 self = h16_to_f8(X4[(size_t)n * 8 + fl]);   // already dinv[n]-scaled
        float acc[8];
#pragma unroll
        for (int j = 0; j < 8; ++j) acc[j] = self.v[j];
        int e0 = offs[n], e1 = offs[n + 1];
        prop_gather8(X4, edge1, e0, e1, fl, slotbase, acc);
        f8 o;
#pragma unroll
        for (int j = 0; j < 8; ++j) {
            float a = fmaf(dn, acc[j], bias8[j]);
            o.v[j] = a;
            s1[j] += a;
            s2[j] = fmaf(a, a, s2[j]);
        }
        Y4[(size_t)n * 8 + fl] = f8_to_h16(o);
    }

    // reduce across the 8 slots (lanes differing in bits 3,4,5)
#pragma unroll
    for (int m = 8; m <= 32; m <<= 1) {
#pragma unroll
        for (int j = 0; j < 8; ++j) {
            s1[j] += __shfl_xor(s1[j], m, 64);
            s2[j] += __shfl_xor(s2[j], m, 64);
        }
    }

    __shared__ float red[4][8][16];
    if (lane < 8) {
#pragma unroll
        for (int j = 0; j < 8; ++j) {
            red[wave][lane][j] = s1[j];
            red[wave][lane][8 + j] = s2[j];
        }
    }
    __syncthreads();
    int t = threadIdx.x;
    if (t < 128) {
        int j = t & 63;            // feature index
        int isq = t >> 6;          // 0 = sum, 1 = sumsq
        int fli = j >> 3, c = (j & 7) + isq * 8;
        float a = red[0][fli][c] + red[1][fli][c] + red[2][fli][c] + red[3][fli][c];
        atomicAdd(&stats[(blockIdx.x & (NSLICE - 1)) * 128 + isq * 64 + j], a);
    }
}

// ------- batchnorm + relu (layer 4 only): fp16 in -> fp16 out + fp8 emit ---
__global__ __launch_bounds__(256) void bn_relu_k(
        const float4* __restrict__ Y4, const float* __restrict__ slices,
        const float* __restrict__ g, const float* __restrict__ be,
        float4* __restrict__ H4, uint2* __restrict__ X8,
        const float* __restrict__ dinv) {
    __shared__ float fs[128];
    int t = threadIdx.x;
    if (t < 128) {
        float s = 0.f;
#pragma unroll
        for (int k = 0; k < NSLICE; ++k) s += slices[k * 128 + t];
        fs[t] = s;
    }
    __syncthreads();
    int i = blockIdx.x * blockDim.x + t;
    if (i >= NN * 8) return;
    int fg = i & 7;                 // feats [fg*8, fg*8+8)
    const float invN = 1.f / (float)NN;
    f8 y = h16_to_f8(Y4[i]);
    float4 gv0 = ((const float4*)g)[fg * 2];
    float4 gv1 = ((const float4*)g)[fg * 2 + 1];
    float4 bv0 = ((const float4*)be)[fg * 2];
    float4 bv1 = ((const float4*)be)[fg * 2 + 1];
    float gv[8] = { gv0.x, gv0.y, gv0.z, gv0.w, gv1.x, gv1.y, gv1.z, gv1.w };
    float bv[8] = { bv0.x, bv0.y, bv0.z, bv0.w, bv1.x, bv1.y, bv1.z, bv1.w };
    f8 o;
#pragma unroll
    for (int j = 0; j < 8; ++j) {
        float m = fs[fg * 8 + j] * invN;
        float v = fs[64 + fg * 8 + j] * invN - m * m;
        float val = fmaf(gv[j] * rsqrtf(v + BN_EPS), y.v[j] - m, bv[j]);
        o.v[j] = val > 0.f ? val : 0.f;
    }
    H4[i] = f8_to_h16(o);
    {
        float dn = dinv[i >> 3];
        float sv[8];
#pragma unroll
        for (int j = 0; j < 8; ++j) sv[j] = dn * o.v[j];
        X8[i] = f_to_fp8x8(sv);
    }
}

// ---- fp8 APPNP: 16 nodes/wave, weight-free, 4+4 ping-pong (low-VGPR) ------
template <bool OUT16>
__global__ __launch_bounds__(256, 3) void appnp8_k(
        const uint4* __restrict__ X8, const float4* __restrict__ H04,
        const int* __restrict__ offs, const int* __restrict__ edge1,
        const float* __restrict__ dinv, const int* __restrict__ perm,
        uint4* __restrict__ Y8, float4* __restrict__ Y16) {
    const int lane = threadIdx.x & 63;
    const int wave = threadIdx.x >> 6;
    const int slot = lane >> 2;
    const int fl = lane & 3;
    const int quadbase = lane & 60;
    const int wid = blockIdx.x * 4 + wave;
    if (wid >= NG16) return;
    int n = perm[wid * 16 + slot];
    float dn = dinv[n];
    float acc[16];
    {
        float self[16];
        fp8x16_to_f(X8[(size_t)n * 4 + fl], self);   // already dinv[n]-scaled
#pragma unroll
        for (int j = 0; j < 16; ++j) acc[j] = self[j];
    }
    int e0 = offs[n], e1 = offs[n + 1];
    if (e0 < e1) {
        int2 d = ((const int2*)(edge1 + e0))[fl];   // 8 edges per slot group
        uint4 ra[4];
#pragma unroll
        for (int k = 0; k < 4; ++k) {
            int s = __shfl((k & 1) ? d.y : d.x, quadbase + (k >> 1), 64);
            ra[k] = X8[(size_t)s * 4 + fl];
        }
        for (int e = e0; e < e1; e += 8) {
            uint4 rb[4];
#pragma unroll
            for (int k = 0; k < 4; ++k) {
                int s = __shfl((k & 1) ? d.y : d.x, quadbase + 2 + (k >> 1), 64);
                rb[k] = X8[(size_t)s * 4 + fl];
            }
            bool more = (e + 8 < e1);
            if (more) d = ((const int2*)(edge1 + e + 8))[fl];
            __builtin_amdgcn_sched_barrier(0);
#pragma unroll
            for (int k = 0; k < 4; ++k) {
                float x[16];
                fp8x16_to_f(ra[k], x);
#pragma unroll
                for (int j = 0; j < 16; ++j) acc[j] += x[j];
            }
            if (more) {
#pragma unroll
                for (int k = 0; k < 4; ++k) {
                    int s = __shfl((k & 1) ? d.y : d.x, quadbase + (k >> 1), 64);
                    ra[k] = X8[(size_t)s * 4 + fl];
                }
            }
            __builtin_amdgcn_sched_barrier(0);
#pragma unroll
            for (int k = 0; k < 4; ++k) {
                float x[16];
                fp8x16_to_f(rb[k], x);
#pragma unroll
                for (int j = 0; j < 16; ++j) acc[j] += x[j];
            }
        }
    }
    // teleport: h0 fp16, feats [fl*16, fl*16+16) = float4 slots fl*2, fl*2+1
    f8 ha = h16_to_f8(H04[(size_t)n * 8 + fl * 2]);
    f8 hb = h16_to_f8(H04[(size_t)n * 8 + fl * 2 + 1]);
    float o[16];
    float s = 0.9f * dn;
#pragma unroll
    for (int j = 0; j < 8; ++j) {
        o[j] = fmaf(s, acc[j], 0.1f * ha.v[j]);
        o[8 + j] = fmaf(s, acc[8 + j], 0.1f * hb.v[j]);
    }
    if (OUT16) {
        f8 lo, hi;
#pragma unroll
        for (int j = 0; j < 8; ++j) { lo.v[j] = o[j]; hi.v[j] = o[8 + j]; }
        Y16[(size_t)n * 8 + fl * 2] = f8_to_h16(lo);
        Y16[(size_t)n * 8 + fl * 2 + 1] = f8_to_h16(hi);
    } else {
        float so[16];
#pragma unroll
        for (int j = 0; j < 16; ++j) so[j] = dn * o[j];
        Y8[(size_t)n * 4 + fl] = f_to_fp8x16(so);
    }
}

// ---------------- FC + log_softmax (fp16 in, fp32 out) ----------------
__global__ __launch_bounds__(256) void final_k(const float2* __restrict__ H2,
                                               const float* __restrict__ Wfc,
                                               const float* __restrict__ bfc,
                                               float* __restrict__ out) {
    const int t = threadIdx.x;
    const int n0 = blockIdx.x * 64;
    const int r0 = (t >> 4) << 2;
    const int c0 = (t & 15) << 2;

    int r[4];
#pragma unroll
    for (int j = 0; j < 4; ++j) {
        int rr = n0 + r0 + j;
        r[j] = rr < NN ? rr : NN - 1;
    }
    const float2* Xr[4];
#pragma unroll
    for (int j = 0; j < 4; ++j) Xr[j] = H2 + (size_t)r[j] * 16;

    float4 bf = *(const float4*)(bfc + c0);
    float acc[4][4];
#pragma unroll
    for (int j = 0; j < 4; ++j) {
        acc[j][0] = bf.x; acc[j][1] = bf.y; acc[j][2] = bf.z; acc[j][3] = bf.w;
    }

#pragma unroll 4
    for (int kq = 0; kq < 16; ++kq) {
        float4 xv[4];
#pragma unroll
        for (int j = 0; j < 4; ++j) xv[j] = h8_to_f4(Xr[j][kq]);
        float4 wv[4];
#pragma unroll
        for (int i = 0; i < 4; ++i)
            wv[i] = *(const float4*)(Wfc + (size_t)(kq * 4 + i) * 64 + c0);
#pragma unroll
        for (int j = 0; j < 4; ++j) {
            acc[j][0] = fmaf(xv[j].x, wv[0].x, acc[j][0]);
            acc[j][1] = fmaf(xv[j].x, wv[0].y, acc[j][1]);
            acc[j][2] = fmaf(xv[j].x, wv[0].z, acc[j][2]);
            acc[j][3] = fmaf(xv[j].x, wv[0].w, acc[j][3]);
            acc[j][0] = fmaf(xv[j].y, wv[1].x, acc[j][0]);
            acc[j][1] = fmaf(xv[j].y, wv[1].y, acc[j][1]);
            acc[j][2] = fmaf(xv[j].y, wv[1].z, acc[j][2]);
            acc[j][3] = fmaf(xv[j].y, wv[1].w, acc[j][3]);
            acc[j][0] = fmaf(xv[j].z, wv[2].x, acc[j][0]);
            acc[j][1] = fmaf(xv[j].z, wv[2].y, acc[j][1]);
            acc[j][2] = fmaf(xv[j].z, wv[2].z, acc[j][2]);
            acc[j][3] = fmaf(xv[j].z, wv[2].w, acc[j][3]);
            acc[j][0] = fmaf(xv[j].w, wv[3].x, acc[j][0]);
            acc[j][1] = fmaf(xv[j].w, wv[3].y, acc[j][1]);
            acc[j][2] = fmaf(xv[j].w, wv[3].z, acc[j][2]);
            acc[j][3] = fmaf(xv[j].w, wv[3].w, acc[j][3]);
        }
    }

#pragma unroll
    for (int j = 0; j < 4; ++j) {
        float m = fmaxf(fmaxf(acc[j][0], acc[j][1]), fmaxf(acc[j][2], acc[j][3]));
#pragma unroll
        for (int d = 1; d <= 8; d <<= 1) m = fmaxf(m, __shfl_xor(m, d, 64));
        float s = expf(acc[j][0] - m) + expf(acc[j][1] - m) +
                  expf(acc[j][2] - m) + expf(acc[j][3] - m);
#pragma unroll
        for (int d = 1; d <= 8; d <<= 1) s += __shfl_xor(s, d, 64);
        float lse = m + logf(s);
        int rr = n0 + r0 + j;
        if (rr < NN)
            *(float4*)(out + (size_t)rr * 64 + c0) =
                make_float4(acc[j][0] - lse, acc[j][1] - lse,
                            acc[j][2] - lse, acc[j][3] - lse);
    }
}

// ---------------- host launch ----------------

static inline char* alignup(char* p, size_t a) {
    return (char*)(((uintptr_t)p + a - 1) & ~(uintptr_t)(a - 1));
}

extern "C" void kernel_launch(void* const* d_in, const int* in_sizes, int n_in,
                              void* d_out, int out_size, void* d_ws, size_t ws_size,
                              hipStream_t stream) {
    const float* x   = (const float*)d_in[0];
    const int*   ei  = (const int*)d_in[1];
    const float* W1  = (const float*)d_in[2];
    const float* b1  = (const float*)d_in[3];
    const float* W2  = (const float*)d_in[4];
    const float* b2  = (const float*)d_in[5];
    const float* Wx  = (const float*)d_in[6];
    const float* bx  = (const float*)d_in[7];
    const float* g1  = (const float*)d_in[8];
    const float* be1 = (const float*)d_in[9];
    const float* g2  = (const float*)d_in[10];
    const float* be2 = (const float*)d_in[11];
    const float* g3  = (const float*)d_in[12];
    const float* be3 = (const float*)d_in[13];
    const float* Wfc = (const float*)d_in[14];
    const float* bfc = (const float*)d_in[15];
    float* out = (float*)d_out;

    const int* srcA = ei;
    const int* dstA = ei + NE;

    char* p = (char*)d_ws;
    float* stats  = (float*)p; p += 4 * NSLICE * 128 * 4;   // 4 layers x 32 slices x 128
    int*   hist   = (int*)p;   p += NBKT * 4;
    int*   bbcur  = (int*)p;   p += 256 * 4;                // bin cursors (zeroed)
    size_t zbytes = (size_t)(p - (char*)d_ws);
    p = alignup(p, 512);
    int*   deg   = (int*)p;    p += NN * 4;         p = alignup(p, 512);
    int*   offs  = (int*)p;    p += (NN + 4) * 4;   p = alignup(p, 512);
    float* dinv  = (float*)p;  p += NN * 4;         p = alignup(p, 512);
    int*   bsum  = (int*)p;    p += 256 * 4;
    int*   bpre  = (int*)p;    p += 256 * 4;
    int*   bcur  = (int*)p;    p += NBKT * 4;       p = alignup(p, 512);
    int*   perm  = (int*)p;    p += NN * 4;         p = alignup(p, 512);
    int*   edge1 = (int*)p;    p += ((size_t)NE + 8 * NN + 256) * 4; p = alignup(p, 512);
    int2*  pairs = (int2*)p;   p += (size_t)NBIN * BCAP * 8; p = alignup(p, 512);
    float4* tmpH = (float4*)p; p += ((size_t)NN + 1) * 128; p = alignup(p, 512);
    float4* hbH  = (float4*)p; p += (size_t)NN * 128;       p = alignup(p, 512);
    float4* apH  = (float4*)p; p += (size_t)NN * 128;       p = alignup(p, 512);
    float4* pbH  = (float4*)p; p += (size_t)NN * 128;       p = alignup(p, 512);
    uint4*  x8a  = (uint4*)p;  p += ((size_t)NN + 1) * 64;  p = alignup(p, 512);
    uint4*  x8b  = (uint4*)p;  p += ((size_t)NN + 1) * 64;

    hipMemsetAsync(d_ws, 0, zbytes, stream);

    // prep: binned scatter first (dynamic cursors), then degree/dinv/hist
    // from the L2-local binned pairs; scans; pad(+zrow); CSR placement.
    binscat_k<<<(NE + EPB - 1) / EPB, 256, 0, stream>>>(srcA, dstA, bbcur, pairs);
    bincnt_k<<<NBIN, 256, 0, stream>>>(pairs, bbcur, deg, dinv, hist);
    scan16_k<<<1, 64, 0, stream>>>(hist, bcur);
    perm_k<<<SCAN_B, 256, 0, stream>>>(deg, bcur, perm);
    scan1_k<<<SCAN_B, 256, 0, stream>>>(deg, offs, bsum);
    scan2_k<<<1, 256, 0, stream>>>(bsum, bpre, offs);
    scan3_k<<<(NN + 255) / 256, 256, 0, stream>>>(offs, bpre);
    pad_k<<<(NN + 255) / 256, 256, 0, stream>>>(deg, offs, edge1, tmpH, x8a, x8b);
    binplace_k<<<NBIN, 256, 0, stream>>>(bbcur, pairs, offs, edge1);

    const int MMG = (NN + 63) / 64;          // 782
    const int PG  = (NGRP + 3) / 4;          // 1563: one octet per wave
    const int AG  = (NG16 + 3) / 4;          // 782:  one 16-group per wave
    const int BNG = (NN * 8 + 255) / 256;    // 1563
    const int SL  = NSLICE * 128;            // floats per layer slice block

    // L1: mm -> prop(stats0)
    mm_k<INF_, false><<<MMG, 256, 0, stream>>>(x, W1, dinv, (float2*)tmpH);
    prop_stats_k<<<PG, 256, 0, stream>>>(tmpH, offs, edge1, dinv, b1, perm, pbH, stats + 0 * SL);
    // L2: BN(stats0,g1,be1) fused into mm(W2) -> prop(stats1)
    mm_bn_k<<<MMG, 256, 0, stream>>>(pbH, stats + 0 * SL, g1, be1, W2, dinv, (float2*)tmpH);
    prop_stats_k<<<PG, 256, 0, stream>>>(tmpH, offs, edge1, dinv, b2, perm, pbH, stats + 1 * SL);
    // L3: BN(stats1,g2,be2) fused into mm(Wx0) -> prop(stats2)
    mm_bn_k<<<MMG, 256, 0, stream>>>(pbH, stats + 1 * SL, g2, be2, Wx, dinv, (float2*)tmpH);
    prop_stats_k<<<PG, 256, 0, stream>>>(tmpH, offs, edge1, dinv, bx, perm, pbH, stats + 2 * SL);
    // L4: BN(stats2,g3,be3) fused into mm(Wx1) -> prop(stats3)
    mm_bn_k<<<MMG, 256, 0, stream>>>(pbH, stats + 2 * SL, g3, be3,
                                     Wx + (size_t)64 * 64, dinv, (float2*)tmpH);
    prop_stats_k<<<PG, 256, 0, stream>>>(tmpH, offs, edge1, dinv, bx + 64, perm,
                                         pbH, stats + 3 * SL);
    // final BN -> H0 (fp16) + fp8 seed
    bn_relu_k<<<BNG, 256, 0, stream>>>(pbH, stats + 3 * SL, g3, be3, hbH, (uint2*)x8a, dinv);

    // APPNP in fp8: 9 fp8->fp8 iters ping-pong; 10th -> fp16 apH
    const uint4* cur8 = x8a;
    for (int it = 0; it < 9; ++it) {
        uint4* o8 = (cur8 == x8a) ? x8b : x8a;
        appnp8_k<false><<<AG, 256, 0, stream>>>(cur8, hbH, offs, edge1, dinv, perm, o8, nullptr);
        cur8 = o8;
    }
    appnp8_k<true><<<AG, 256, 0, stream>>>(cur8, hbH, offs, edge1, dinv, perm, nullptr, apH);

    final_k<<<MMG, 256, 0, stream>>>((const float2*)apH, Wfc, bfc, out);
}

// Round 13
// 420.028 us; speedup vs baseline: 4.4166x; 1.0145x over previous
//
#include <hip/hip_runtime.h>
#include <hip/hip_fp16.h>
#include <cstdint>
#include <cstddef>

#define NN 50000
#define NE 800000
#define HID 64
#define INF_ 128
#define BN_EPS 1e-5f
#define NGRP (NN / 8)        // 6250 node-octets for fp16 props
#define NG16 (NN / 16)       // 3125 node-16-groups for fp8 APPNP
#define SCAN_B 196           // ceil(50000/256)
#define NSLICE 32            // stats partial slices (contention fix)
#define NBKT 16              // degree buckets (chunk count = ceil(deg/8), capped)
#define NBIN 196             // dst bins of 256 nodes
#define EPB 2048             // edges per binscat block
#define BCAP 5120            // bin capacity: mean 4096 + 16 sigma (64)

typedef float floatx2 __attribute__((ext_vector_type(2)));

// ---------------- fp16 pack/unpack ----------------
__device__ __forceinline__ float4 h8_to_f4(float2 raw) {
    union { float f; __half2 h; } ua, ub;
    ua.f = raw.x; ub.f = raw.y;
    float2 fa = __half22float2(ua.h), fb = __half22float2(ub.h);
    return make_float4(fa.x, fa.y, fb.x, fb.y);
}
__device__ __forceinline__ float2 f4_to_h8(float4 v) {
    union { float f; __half2 h; } ua, ub;
    ua.h = __float22half2_rn(make_float2(v.x, v.y));
    ub.h = __float22half2_rn(make_float2(v.z, v.w));
    return make_float2(ua.f, ub.f);
}
struct f8 { float v[8]; };
__device__ __forceinline__ f8 h16_to_f8(float4 raw) {
    f8 r;
    union { float f; __half2 h; } u;
    float2 a;
    u.f = raw.x; a = __half22float2(u.h); r.v[0] = a.x; r.v[1] = a.y;
    u.f = raw.y; a = __half22float2(u.h); r.v[2] = a.x; r.v[3] = a.y;
    u.f = raw.z; a = __half22float2(u.h); r.v[4] = a.x; r.v[5] = a.y;
    u.f = raw.w; a = __half22float2(u.h); r.v[6] = a.x; r.v[7] = a.y;
    return r;
}
__device__ __forceinline__ float4 f8_to_h16(const f8& s) {
    union { float f; __half2 h; } u;
    float4 o;
    u.h = __float22half2_rn(make_float2(s.v[0], s.v[1])); o.x = u.f;
    u.h = __float22half2_rn(make_float2(s.v[2], s.v[3])); o.y = u.f;
    u.h = __float22half2_rn(make_float2(s.v[4], s.v[5])); o.z = u.f;
    u.h = __float22half2_rn(make_float2(s.v[6], s.v[7])); o.w = u.f;
    return o;
}

// ---------------- fp8 e4m3 (OCP, gfx950 HW cvt) pack/unpack ----------------
__device__ __forceinline__ void fp8x8_to_f(unsigned lo, unsigned hi, float out[8]) {
    floatx2 a = __builtin_amdgcn_cvt_pk_f32_fp8((int)lo, false);
    floatx2 b = __builtin_amdgcn_cvt_pk_f32_fp8((int)lo, true);
    floatx2 c = __builtin_amdgcn_cvt_pk_f32_fp8((int)hi, false);
    floatx2 d = __builtin_amdgcn_cvt_pk_f32_fp8((int)hi, true);
    out[0] = a[0]; out[1] = a[1]; out[2] = b[0]; out[3] = b[1];
    out[4] = c[0]; out[5] = c[1]; out[6] = d[0]; out[7] = d[1];
}
__device__ __forceinline__ void fp8x16_to_f(uint4 r, float out[16]) {
    fp8x8_to_f(r.x, r.y, out);
    fp8x8_to_f(r.z, r.w, out + 8);
}
__device__ __forceinline__ uint2 f_to_fp8x8(const float v[8]) {
    int w0 = __builtin_amdgcn_cvt_pk_fp8_f32(v[0], v[1], 0, false);
    w0 = __builtin_amdgcn_cvt_pk_fp8_f32(v[2], v[3], w0, true);
    int w1 = __builtin_amdgcn_cvt_pk_fp8_f32(v[4], v[5], 0, false);
    w1 = __builtin_amdgcn_cvt_pk_fp8_f32(v[6], v[7], w1, true);
    uint2 o; o.x = (unsigned)w0; o.y = (unsigned)w1;
    return o;
}
__device__ __forceinline__ uint4 f_to_fp8x16(const float v[16]) {
    uint2 a = f_to_fp8x8(v), b = f_to_fp8x8(v + 8);
    uint4 o; o.x = a.x; o.y = a.y; o.z = b.x; o.w = b.y;
    return o;
}

// ---------------- graph prep ----------------

// pass A (FIRST kernel): LDS bucket sort of EPB edges into NBIN dst-bins,
// dynamic per-bin global cursors, fixed-capacity bin regions (b*BCAP).
__global__ __launch_bounds__(256) void binscat_k(
        const int* __restrict__ src, const int* __restrict__ dst,
        int* __restrict__ bcur, int2* __restrict__ pairs) {
    __shared__ int lcnt[256], lscan[256], lexc[256], gbase[256];
    __shared__ int2 stage[EPB];
    const int t = threadIdx.x;
    const int base = blockIdx.x * EPB;
    lcnt[t] = 0;
    __syncthreads();
    int2 mypair[EPB / 256];
    int mybin[EPB / 256], myr[EPB / 256];
#pragma unroll
    for (int i = 0; i < EPB / 256; ++i) {
        int e = base + i * 256 + t;
        if (e < NE) {
            int s = src[e], d = dst[e];
            mypair[i] = make_int2(s, d);
            mybin[i] = d >> 8;
            myr[i] = atomicAdd(&lcnt[mybin[i]], 1);
        } else mybin[i] = -1;
    }
    __syncthreads();
    lscan[t] = lcnt[t];
    __syncthreads();
    for (int d = 1; d < 256; d <<= 1) {
        int u = (t >= d) ? lscan[t - d] : 0;
        __syncthreads();
        lscan[t] += u;
        __syncthreads();
    }
    lexc[t] = lscan[t] - lcnt[t];
    if (lcnt[t] > 0) gbase[t] = atomicAdd(&bcur[t], lcnt[t]);
    __syncthreads();
#pragma unroll
    for (int i = 0; i < EPB / 256; ++i)
        if (mybin[i] >= 0) stage[lexc[mybin[i]] + myr[i]] = mypair[i];
    __syncthreads();
    const int total = lscan[255];
#pragma unroll
    for (int i = 0; i < EPB / 256; ++i) {
        int s = i * 256 + t;
        if (s < total) {
            int2 pr = stage[s];
            int b = pr.y >> 8;
            pairs[(size_t)b * BCAP + gbase[b] + (s - lexc[b])] = pr;
        }
    }
}

// per-bin degree count from binned pairs (LDS atomics, L2-local reads);
// epilogue also emits dinv and the degree-bucket histogram.
__global__ __launch_bounds__(256) void bincnt_k(
        const int2* __restrict__ pairs, const int* __restrict__ bcur,
        int* __restrict__ deg, float* __restrict__ dinv, int* __restrict__ hist) {
    __shared__ int lc[256];
    __shared__ int lh[NBKT];
    const int b = blockIdx.x, t = threadIdx.x;
    lc[t] = 0;
    if (t < NBKT) lh[t] = 0;
    __syncthreads();
    const int cnt = bcur[b];
    const size_t s0 = (size_t)b * BCAP;
    for (int s = t; s < cnt; s += 256)
        atomicAdd(&lc[pairs[s0 + s].y & 255], 1);
    __syncthreads();
    int n = b * 256 + t;
    if (n < NN) {
        int d = lc[t];
        deg[n] = d;
        dinv[n] = rsqrtf((float)(d + 1));        // +1 self-loop
        int c = (d + 7) >> 3;
        if (c > NBKT - 1) c = NBKT - 1;
        atomicAdd(&lh[c], 1);
    }
    __syncthreads();
    if (t < NBKT && lh[t]) atomicAdd(&hist[t], lh[t]);
}

// fused: padded-degree block scan (scan1) + degree-bucket permutation (perm).
// Each block derives the 16-entry bucket prefix from hist redundantly and
// reserves its chunk via zeroed global cursors bktcur.
__global__ __launch_bounds__(256) void scan1perm_k(
        const int* __restrict__ deg, const int* __restrict__ hist,
        int* __restrict__ offs, int* __restrict__ bsum,
        int* __restrict__ bktcur, int* __restrict__ perm) {
    __shared__ int sh[256];
    __shared__ int lh[NBKT], lbase[NBKT];
    const int t = threadIdx.x, b = blockIdx.x;
    const int i = b * 256 + t;
    const int dg = (i < NN) ? deg[i] : 0;
    // ---- perm part ----
    if (t < NBKT) lh[t] = 0;
    __syncthreads();
    int c = 0, r = 0;
    if (i < NN) {
        c = (dg + 7) >> 3;
        if (c > NBKT - 1) c = NBKT - 1;
        r = atomicAdd(&lh[c], 1);
    }
    __syncthreads();
    if (t < NBKT) {
        int s = 0;
        for (int k = 0; k < t; ++k) s += hist[k];   // 16-entry prefix, redundant
        lbase[t] = s + (lh[t] ? atomicAdd(&bktcur[t], lh[t]) : 0);
    }
    __syncthreads();
    if (i < NN) perm[lbase[c] + r] = i;
    // ---- scan1 part (padded degree block scan) ----
    int v = (i < NN) ? ((dg + 7) & ~7) : 0;
    sh[t] = v;
    __syncthreads();
    for (int d = 1; d < 256; d <<= 1) {
        int u = (t >= d) ? sh[t - d] : 0;
        __syncthreads();
        sh[t] += u;
        __syncthreads();
    }
    if (i < NN) offs[i] = sh[t] - v;
    if (t == 255) bsum[b] = sh[255];
}

// fused scan2+scan3: every block redundantly scans the 196 block sums in LDS
// and applies its own exclusive prefix; block covering i==NN writes offs[NN].
__global__ __launch_bounds__(256) void scan23_k(
        const int* __restrict__ bsum, int* __restrict__ offs) {
    __shared__ int sh[256];
    const int t = threadIdx.x, b = blockIdx.x;
    int v = (t < SCAN_B) ? bsum[t] : 0;
    sh[t] = v;
    __syncthreads();
    for (int d = 1; d < 256; d <<= 1) {
        int u = (t >= d) ? sh[t - d] : 0;
        __syncthreads();
        sh[t] += u;
        __syncthreads();
    }
    const int bpre = (b > 0) ? sh[b - 1] : 0;
    const int total = sh[SCAN_B - 1];
    const int i = b * 256 + t;
    if (i < NN) offs[i] += bpre;
    if (i == NN) offs[NN] = total;
}

// pass B + pad + zrow: place edges into CSR (per-bin L2-local window);
// afterwards lcur[t] == deg[n], so the same block pads the CSR tail.
__global__ __launch_bounds__(256) void binplace_pad_k(
        const int* __restrict__ bcur, const int2* __restrict__ pairs,
        const int* __restrict__ offs, int* __restrict__ edge1,
        float4* __restrict__ tmpH, uint4* __restrict__ x8a,
        uint4* __restrict__ x8b) {
    __shared__ int lcur[256];
    const int b = blockIdx.x, t = threadIdx.x;
    if (b == 0) {
        if (t < 8) tmpH[(size_t)NN * 8 + t] = make_float4(0.f, 0.f, 0.f, 0.f);
        else if (t < 12) x8a[(size_t)NN * 4 + (t - 8)] = make_uint4(0, 0, 0, 0);
        else if (t < 16) x8b[(size_t)NN * 4 + (t - 12)] = make_uint4(0, 0, 0, 0);
    }
    lcur[t] = 0;
    __syncthreads();
    const int cnt = bcur[b];
    const size_t s0 = (size_t)b * BCAP;
    for (int s = t; s < cnt; s += 256) {
        int2 pr = pairs[s0 + s];
        int d = pr.y;
        int slot = atomicAdd(&lcur[d & 255], 1);
        edge1[offs[d] + slot] = pr.x;
    }
    __syncthreads();
    int n = b * 256 + t;
    if (n < NN) {
        int e = offs[n] + lcur[t], e1 = offs[n + 1];
        for (; e < e1; ++e) edge1[e] = NN;   // pad -> all-zero row
    }
}

// ------ dense matmul: Y[N,64] = dinv[n] * (X[N,K] @ W[K,64]), fp16 out -----
template <int K, bool HIN>
__global__ __launch_bounds__(256, 2) void mm_k(const void* __restrict__ Xv,
                                               const float* __restrict__ W,
                                               const float* __restrict__ dinv,
                                               float2* __restrict__ Y) {
    constexpr int RS = K + 4;            // LDS row stride (floats); keeps 16B align
    __shared__ float Xs[64 * RS];
    __shared__ float Ws[K * 64];
    const int t = threadIdx.x;
    const int n0 = blockIdx.x * 64;

    // stage W: K*16 float4, coalesced
    {
        const float4* Wg = (const float4*)W;
        for (int g2 = t; g2 < K * 16; g2 += 256) {
            int row = g2 >> 4, c4 = g2 & 15;
            *(float4*)&Ws[row * 64 + c4 * 4] = Wg[g2];
        }
    }
    // stage X tile (clamped rows for the tail block)
    if (HIN) {
        const float4* Xg = (const float4*)Xv;      // 8 halves per float4
        for (int g2 = t; g2 < 64 * (K / 8); g2 += 256) {
            int row = g2 / (K / 8), c8 = g2 % (K / 8);
            int rr = n0 + row; if (rr >= NN) rr = NN - 1;
            f8 v = h16_to_f8(Xg[(size_t)rr * (K / 8) + c8]);
            float* dp = &Xs[row * RS + c8 * 8];
#pragma unroll
            for (int j = 0; j < 8; ++j) dp[j] = v.v[j];
        }
    } else {
        const float4* Xg = (const float4*)Xv;
        for (int g2 = t; g2 < 64 * (K / 4); g2 += 256) {
            int row = g2 / (K / 4), c4 = g2 % (K / 4);
            int rr = n0 + row; if (rr >= NN) rr = NN - 1;
            *(float4*)&Xs[row * RS + c4 * 4] = Xg[(size_t)rr * (K / 4) + c4];
        }
    }
    __syncthreads();

    const int r0 = (t >> 4) << 2;
    const int c0 = (t & 15) << 2;
    float acc[4][4];
#pragma unroll
    for (int j = 0; j < 4; ++j)
#pragma unroll
        for (int c = 0; c < 4; ++c) acc[j][c] = 0.f;

#pragma unroll 8
    for (int kq = 0; kq < K / 4; ++kq) {
        float4 xv[4];
#pragma unroll
        for (int j = 0; j < 4; ++j)
            xv[j] = *(const float4*)&Xs[(r0 + j) * RS + kq * 4];
        float4 wv[4];
#pragma unroll
        for (int i = 0; i < 4; ++i)
            wv[i] = *(const float4*)&Ws[(kq * 4 + i) * 64 + c0];
#pragma unroll
        for (int j = 0; j < 4; ++j) {
            acc[j][0] = fmaf(xv[j].x, wv[0].x, acc[j][0]);
            acc[j][1] = fmaf(xv[j].x, wv[0].y, acc[j][1]);
            acc[j][2] = fmaf(xv[j].x, wv[0].z, acc[j][2]);
            acc[j][3] = fmaf(xv[j].x, wv[0].w, acc[j][3]);
            acc[j][0] = fmaf(xv[j].y, wv[1].x, acc[j][0]);
            acc[j][1] = fmaf(xv[j].y, wv[1].y, acc[j][1]);
            acc[j][2] = fmaf(xv[j].y, wv[1].z, acc[j][2]);
            acc[j][3] = fmaf(xv[j].y, wv[1].w, acc[j][3]);
            acc[j][0] = fmaf(xv[j].z, wv[2].x, acc[j][0]);
            acc[j][1] = fmaf(xv[j].z, wv[2].y, acc[j][1]);
            acc[j][2] = fmaf(xv[j].z, wv[2].z, acc[j][2]);
            acc[j][3] = fmaf(xv[j].z, wv[2].w, acc[j][3]);
            acc[j][0] = fmaf(xv[j].w, wv[3].x, acc[j][0]);
            acc[j][1] = fmaf(xv[j].w, wv[3].y, acc[j][1]);
            acc[j][2] = fmaf(xv[j].w, wv[3].z, acc[j][2]);
            acc[j][3] = fmaf(xv[j].w, wv[3].w, acc[j][3]);
        }
    }

#pragma unroll
    for (int j = 0; j < 4; ++j) {
        int rr = n0 + r0 + j;
        if (rr < NN) {
            float dn = dinv[rr];
            Y[(size_t)rr * 16 + (t & 15)] =
                f4_to_h8(make_float4(acc[j][0] * dn, acc[j][1] * dn,
                                     acc[j][2] * dn, acc[j][3] * dn));
        }
    }
}

// ---- fused BN+ReLU -> matmul (K=64): replaces 3 bn_relu passes ------------
__global__ __launch_bounds__(256, 2) void mm_bn_k(
        const float4* __restrict__ Y4in, const float* __restrict__ slices,
        const float* __restrict__ gg, const float* __restrict__ be,
        const float* __restrict__ W, const float* __restrict__ dinv,
        float2* __restrict__ Y) {
    constexpr int K = 64, RS = K + 4;
    __shared__ float Xs[64 * RS];
    __shared__ float Ws[K * 64];
    __shared__ float fs[128], gs[64], bs[64];
    const int t = threadIdx.x;
    const int n0 = blockIdx.x * 64;

    if (t < 128) {
        float s = 0.f;
#pragma unroll
        for (int k = 0; k < NSLICE; ++k) s += slices[k * 128 + t];
        fs[t] = s;
    } else if (t < 192) {
        gs[t - 128] = gg[t - 128];
    } else {
        bs[t - 192] = be[t - 192];
    }
    {
        const float4* Wg = (const float4*)W;
        for (int g2 = t; g2 < K * 16; g2 += 256) {
            int row = g2 >> 4, c4 = g2 & 15;
            *(float4*)&Ws[row * 64 + c4 * 4] = Wg[g2];
        }
    }
    __syncthreads();

    const float invN = 1.f / (float)NN;
    for (int g2 = t; g2 < 64 * 8; g2 += 256) {
        int row = g2 >> 3, c8 = g2 & 7;
        int rr = n0 + row; if (rr >= NN) rr = NN - 1;
        f8 v = h16_to_f8(Y4in[(size_t)rr * 8 + c8]);
        float* dp = &Xs[row * RS + c8 * 8];
#pragma unroll
        for (int j = 0; j < 8; ++j) {
            int f = c8 * 8 + j;
            float m = fs[f] * invN;
            float va = fs[64 + f] * invN - m * m;
            float val = fmaf(gs[f] * rsqrtf(va + BN_EPS), v.v[j] - m, bs[f]);
            dp[j] = val > 0.f ? val : 0.f;
        }
    }
    __syncthreads();

    const int r0 = (t >> 4) << 2;
    const int c0 = (t & 15) << 2;
    float acc[4][4];
#pragma unroll
    for (int j = 0; j < 4; ++j)
#pragma unroll
        for (int c = 0; c < 4; ++c) acc[j][c] = 0.f;

#pragma unroll 8
    for (int kq = 0; kq < K / 4; ++kq) {
        float4 xv[4];
#pragma unroll
        for (int j = 0; j < 4; ++j)
            xv[j] = *(const float4*)&Xs[(r0 + j) * RS + kq * 4];
        float4 wv[4];
#pragma unroll
        for (int i = 0; i < 4; ++i)
            wv[i] = *(const float4*)&Ws[(kq * 4 + i) * 64 + c0];
#pragma unroll
        for (int j = 0; j < 4; ++j) {
            acc[j][0] = fmaf(xv[j].x, wv[0].x, acc[j][0]);
            acc[j][1] = fmaf(xv[j].x, wv[0].y, acc[j][1]);
            acc[j][2] = fmaf(xv[j].x, wv[0].z, acc[j][2]);
            acc[j][3] = fmaf(xv[j].x, wv[0].w, acc[j][3]);
            acc[j][0] = fmaf(xv[j].y, wv[1].x, acc[j][0]);
            acc[j][1] = fmaf(xv[j].y, wv[1].y, acc[j][1]);
            acc[j][2] = fmaf(xv[j].y, wv[1].z, acc[j][2]);
            acc[j][3] = fmaf(xv[j].y, wv[1].w, acc[j][3]);
            acc[j][0] = fmaf(xv[j].z, wv[2].x, acc[j][0]);
            acc[j][1] = fmaf(xv[j].z, wv[2].y, acc[j][1]);
            acc[j][2] = fmaf(xv[j].z, wv[2].z, acc[j][2]);
            acc[j][3] = fmaf(xv[j].z, wv[2].w, acc[j][3]);
            acc[j][0] = fmaf(xv[j].w, wv[3].x, acc[j][0]);
            acc[j][1] = fmaf(xv[j].w, wv[3].y, acc[j][1]);
            acc[j][2] = fmaf(xv[j].w, wv[3].z, acc[j][2]);
            acc[j][3] = fmaf(xv[j].w, wv[3].w, acc[j][3]);
        }
    }

#pragma unroll
    for (int j = 0; j < 4; ++j) {
        int rr = n0 + r0 + j;
        if (rr < NN) {
            float dn = dinv[rr];
            Y[(size_t)rr * 16 + (t & 15)] =
                f4_to_h8(make_float4(acc[j][0] * dn, acc[j][1] * dn,
                                     acc[j][2] * dn, acc[j][3] * dn));
        }
    }
}

// ---- fp16 propagate core: weight-free, 4+4 ping-pong (low-VGPR) -----------
__device__ __forceinline__ void prop_gather8(const float4* __restrict__ X4,
                                             const int* __restrict__ E,
                                             int e0, int e1, int fl, int slotbase,
                                             float acc[8]) {
    if (e0 >= e1) return;
    int d = E[e0 + fl];                 // 8 edge idxs for this slot group
    float4 ra[4];
#pragma unroll
    for (int i = 0; i < 4; ++i) {
        int s = __shfl(d, slotbase + i, 64);
        ra[i] = X4[(size_t)s * 8 + fl];
    }
    for (int e = e0; e < e1; e += 8) {
        float4 rb[4];
#pragma unroll
        for (int i = 0; i < 4; ++i) {
            int s = __shfl(d, slotbase + 4 + i, 64);
            rb[i] = X4[(size_t)s * 8 + fl];
        }
        bool more = (e + 8 < e1);
        if (more) d = E[e + 8 + fl];    // prefetch next block's indices
        __builtin_amdgcn_sched_barrier(0);
#pragma unroll
        for (int i = 0; i < 4; ++i) {
            f8 x = h16_to_f8(ra[i]);
#pragma unroll
            for (int j = 0; j < 8; ++j) acc[j] += x.v[j];
        }
        if (more) {
#pragma unroll
            for (int i = 0; i < 4; ++i) {
                int s = __shfl(d, slotbase + i, 64);
                ra[i] = X4[(size_t)s * 8 + fl];
            }
        }
        __builtin_amdgcn_sched_barrier(0);
#pragma unroll
        for (int i = 0; i < 4; ++i) {
            f8 x = h16_to_f8(rb[i]);
#pragma unroll
            for (int j = 0; j < 8; ++j) acc[j] += x.v[j];
        }
    }
}

// ---------------- propagate + bias + BN-stats (fp16 in, fp16 out) ----------
__global__ __launch_bounds__(256, 3) void prop_stats_k(
        const float4* __restrict__ X4, const int* __restrict__ offs,
        const int* __restrict__ edge1, const float* __restrict__ dinv,
        const float* __restrict__ bias, const int* __restrict__ perm,
        float4* __restrict__ Y4, float* __restrict__ stats) {
    const int lane = threadIdx.x & 63;
    const int wave = threadIdx.x >> 6;
    const int slot = lane >> 3;
    const int fl = lane & 7;
    const int slotbase = lane & 56;
    const int wid = blockIdx.x * 4 + wave;
    const int nw = gridDim.x * 4;

    float bias8[8];
    {
        float4 b0 = ((const float4*)bias)[fl * 2];
        float4 b1 = ((const float4*)bias)[fl * 2 + 1];
        bias8[0] = b0.x; bias8[1] = b0.y; bias8[2] = b0.z; bias8[3] = b0.w;
        bias8[4] = b1.x; bias8[5] = b1.y; bias8[6] = b1.z; bias8[7] = b1.w;
    }

    float s1[8], s2[8];
#pragma unroll
    for (int j = 0; j < 8; ++j) { s1[j] = 0.f; s2[j] = 0.f; }

    for (int g = wid; g < NGRP; g += nw) {
        int n = perm[g * 8 + slot];
        float dn = dinv[n];
        f8 self = h16_to_f8(X4[(size_t)n * 8 + fl]);   // already dinv[n]-scaled
        float acc[8];
#pragma unroll
        for (int j = 0; j < 8; ++j) acc[j] = self.v[j];
        int e0 = offs[n], e1 = offs[n + 1];
        prop_gather8(X4, edge1, e0, e1, fl, slotbase, acc);
        f8 o;
#pragma unroll
        for (int j = 0; j < 8; ++j) {
            float a = fmaf(dn, acc[j], bias8[j]);
            o.v[j] = a;
            s1[j] += a;
            s2[j] = fmaf(a, a, s2[j]);
        }
        Y4[(size_t)n * 8 + fl] = f8_to_h16(o);
    }

    // reduce across the 8 slots (lanes differing in bits 3,4,5)
#pragma unroll
    for (int m = 8; m <= 32; m <<= 1) {
#pragma unroll
        for (int j = 0; j < 8; ++j) {
            s1[j] += __shfl_xor(s1[j], m, 64);
            s2[j] += __shfl_xor(s2[j], m, 64);
        }
    }

    __shared__ float red[4][8][16];
    if (lane < 8) {
#pragma unroll
        for (int j = 0; j < 8; ++j) {
            red[wave][lane][j] = s1[j];
            red[wave][lane][8 + j] = s2[j];
        }
    }
    __syncthreads();
    int t = threadIdx.x;
    if (t < 128) {
        int j = t & 63;            // feature index
        int isq = t >> 6;          // 0 = sum, 1 = sumsq
        int fli = j >> 3, c = (j & 7) + isq * 8;
        float a = red[0][fli][c] + red[1][fli][c] + red[2][fli][c] + red[3][fli][c];
        atomicAdd(&stats[(blockIdx.x & (NSLICE - 1)) * 128 + isq * 64 + j], a);
    }
}

// ------- batchnorm + relu (layer 4 only): fp16 in -> fp16 out + fp8 emit ---
__global__ __launch_bounds__(256) void bn_relu_k(
        const float4* __restrict__ Y4, const float* __restrict__ slices,
        const float* __restrict__ g, const float* __restrict__ be,
        float4* __restrict__ H4, uint2* __restrict__ X8,
        const float* __restrict__ dinv) {
    __shared__ float fs[128];
    int t = threadIdx.x;
    if (t < 128) {
        float s = 0.f;
#pragma unroll
        for (int k = 0; k < NSLICE; ++k) s += slices[k * 128 + t];
        fs[t] = s;
    }
    __syncthreads();
    int i = blockIdx.x * blockDim.x + t;
    if (i >= NN * 8) return;
    int fg = i & 7;                 // feats [fg*8, fg*8+8)
    const float invN = 1.f / (float)NN;
    f8 y = h16_to_f8(Y4[i]);
    float4 gv0 = ((const float4*)g)[fg * 2];
    float4 gv1 = ((const float4*)g)[fg * 2 + 1];
    float4 bv0 = ((const float4*)be)[fg * 2];
    float4 bv1 = ((const float4*)be)[fg * 2 + 1];
    float gv[8] = { gv0.x, gv0.y, gv0.z, gv0.w, gv1.x, gv1.y, gv1.z, gv1.w };
    float bv[8] = { bv0.x, bv0.y, bv0.z, bv0.w, bv1.x, bv1.y, bv1.z, bv1.w };
    f8 o;
#pragma unroll
    for (int j = 0; j < 8; ++j) {
        float m = fs[fg * 8 + j] * invN;
        float v = fs[64 + fg * 8 + j] * invN - m * m;
        float val = fmaf(gv[j] * rsqrtf(v + BN_EPS), y.v[j] - m, bv[j]);
        o.v[j] = val > 0.f ? val : 0.f;
    }
    H4[i] = f8_to_h16(o);
    {
        float dn = dinv[i >> 3];
        float sv[8];
#pragma unroll
        for (int j = 0; j < 8; ++j) sv[j] = dn * o.v[j];
        X8[i] = f_to_fp8x8(sv);
    }
}

// ---- fp8 APPNP: 16 nodes/wave, weight-free, 4+4 ping-pong (low-VGPR) ------
template <bool OUT16>
__global__ __launch_bounds__(256, 3) void appnp8_k(
        const uint4* __restrict__ X8, const float4* __restrict__ H04,
        const int* __restrict__ offs, const int* __restrict__ edge1,
        const float* __restrict__ dinv, const int* __restrict__ perm,
        uint4* __restrict__ Y8, float4* __restrict__ Y16) {
    const int lane = threadIdx.x & 63;
    const int wave = threadIdx.x >> 6;
    const int slot = lane >> 2;
    const int fl = lane & 3;
    const int quadbase = lane & 60;
    const int wid = blockIdx.x * 4 + wave;
    if (wid >= NG16) return;
    int n = perm[wid * 16 + slot];
    float dn = dinv[n];
    float acc[16];
    {
        float self[16];
        fp8x16_to_f(X8[(size_t)n * 4 + fl], self);   // already dinv[n]-scaled
#pragma unroll
        for (int j = 0; j < 16; ++j) acc[j] = self[j];
    }
    int e0 = offs[n], e1 = offs[n + 1];
    if (e0 < e1) {
        int2 d = ((const int2*)(edge1 + e0))[fl];   // 8 edges per slot group
        uint4 ra[4];
#pragma unroll
        for (int k = 0; k < 4; ++k) {
            int s = __shfl((k & 1) ? d.y : d.x, quadbase + (k >> 1), 64);
            ra[k] = X8[(size_t)s * 4 + fl];
        }
        for (int e = e0; e < e1; e += 8) {
            uint4 rb[4];
#pragma unroll
            for (int k = 0; k < 4; ++k) {
                int s = __shfl((k & 1) ? d.y : d.x, quadbase + 2 + (k >> 1), 64);
                rb[k] = X8[(size_t)s * 4 + fl];
            }
            bool more = (e + 8 < e1);
            if (more) d = ((const int2*)(edge1 + e + 8))[fl];
            __builtin_amdgcn_sched_barrier(0);
#pragma unroll
            for (int k = 0; k < 4; ++k) {
                float x[16];
                fp8x16_to_f(ra[k], x);
#pragma unroll
                for (int j = 0; j < 16; ++j) acc[j] += x[j];
            }
            if (more) {
#pragma unroll
                for (int k = 0; k < 4; ++k) {
                    int s = __shfl((k & 1) ? d.y : d.x, quadbase + (k >> 1), 64);
                    ra[k] = X8[(size_t)s * 4 + fl];
                }
            }
            __builtin_amdgcn_sched_barrier(0);
#pragma unroll
            for (int k = 0; k < 4; ++k) {
                float x[16];
                fp8x16_to_f(rb[k], x);
#pragma unroll
                for (int j = 0; j < 16; ++j) acc[j] += x[j];
            }
        }
    }
    // teleport: h0 fp16, feats [fl*16, fl*16+16) = float4 slots fl*2, fl*2+1
    f8 ha = h16_to_f8(H04[(size_t)n * 8 + fl * 2]);
    f8 hb = h16_to_f8(H04[(size_t)n * 8 + fl * 2 + 1]);
    float o[16];
    float s = 0.9f * dn;
#pragma unroll
    for (int j = 0; j < 8; ++j) {
        o[j] = fmaf(s, acc[j], 0.1f * ha.v[j]);
        o[8 + j] = fmaf(s, acc[8 + j], 0.1f * hb.v[j]);
    }
    if (OUT16) {
        f8 lo, hi;
#pragma unroll
        for (int j = 0; j < 8; ++j) { lo.v[j] = o[j]; hi.v[j] = o[8 + j]; }
        Y16[(size_t)n * 8 + fl * 2] = f8_to_h16(lo);
        Y16[(size_t)n * 8 + fl * 2 + 1] = f8_to_h16(hi);
    } else {
        float so[16];
#pragma unroll
        for (int j = 0; j < 16; ++j) so[j] = dn * o[j];
        Y8[(size_t)n * 4 + fl] = f_to_fp8x16(so);
    }
}

// ---------------- FC + log_softmax (fp16 in, fp32 out) ----------------
__global__ __launch_bounds__(256) void final_k(const float2* __restrict__ H2,
                                               const float* __restrict__ Wfc,
                                               const float* __restrict__ bfc,
                                               float* __restrict__ out) {
    const int t = threadIdx.x;
    const int n0 = blockIdx.x * 64;
    const int r0 = (t >> 4) << 2;
    const int c0 = (t & 15) << 2;

    int r[4];
#pragma unroll
    for (int j = 0; j < 4; ++j) {
        int rr = n0 + r0 + j;
        r[j] = rr < NN ? rr : NN - 1;
    }
    const float2* Xr[4];
#pragma unroll
    for (int j = 0; j < 4; ++j) Xr[j] = H2 + (size_t)r[j] * 16;

    float4 bf = *(const float4*)(bfc + c0);
    float acc[4][4];
#pragma unroll
    for (int j = 0; j < 4; ++j) {
        acc[j][0] = bf.x; acc[j][1] = bf.y; acc[j][2] = bf.z; acc[j][3] = bf.w;
    }

#pragma unroll 4
    for (int kq = 0; kq < 16; ++kq) {
        float4 xv[4];
#pragma unroll
        for (int j = 0; j < 4; ++j) xv[j] = h8_to_f4(Xr[j][kq]);
        float4 wv[4];
#pragma unroll
        for (int i = 0; i < 4; ++i)
            wv[i] = *(const float4*)(Wfc + (size_t)(kq * 4 + i) * 64 + c0);
#pragma unroll
        for (int j = 0; j < 4; ++j) {
            acc[j][0] = fmaf(xv[j].x, wv[0].x, acc[j][0]);
            acc[j][1] = fmaf(xv[j].x, wv[0].y, acc[j][1]);
            acc[j][2] = fmaf(xv[j].x, wv[0].z, acc[j][2]);
            acc[j][3] = fmaf(xv[j].x, wv[0].w, acc[j][3]);
            acc[j][0] = fmaf(xv[j].y, wv[1].x, acc[j][0]);
            acc[j][1] = fmaf(xv[j].y, wv[1].y, acc[j][1]);
            acc[j][2] = fmaf(xv[j].y, wv[1].z, acc[j][2]);
            acc[j][3] = fmaf(xv[j].y, wv[1].w, acc[j][3]);
            acc[j][0] = fmaf(xv[j].z, wv[2].x, acc[j][0]);
            acc[j][1] = fmaf(xv[j].z, wv[2].y, acc[j][1]);
            acc[j][2] = fmaf(xv[j].z, wv[2].z, acc[j][2]);
            acc[j][3] = fmaf(xv[j].z, wv[2].w, acc[j][3]);
            acc[j][0] = fmaf(xv[j].w, wv[3].x, acc[j][0]);
            acc[j][1] = fmaf(xv[j].w, wv[3].y, acc[j][1]);
            acc[j][2] = fmaf(xv[j].w, wv[3].z, acc[j][2]);
            acc[j][3] = fmaf(xv[j].w, wv[3].w, acc[j][3]);
        }
    }

#pragma unroll
    for (int j = 0; j < 4; ++j) {
        float m = fmaxf(fmaxf(acc[j][0], acc[j][1]), fmaxf(acc[j][2], acc[j][3]));
#pragma unroll
        for (int d = 1; d <= 8; d <<= 1) m = fmaxf(m, __shfl_xor(m, d, 64));
        float s = expf(acc[j][0] - m) + expf(acc[j][1] - m) +
                  expf(acc[j][2] - m) + expf(acc[j][3] - m);
#pragma unroll
        for (int d = 1; d <= 8; d <<= 1) s += __shfl_xor(s, d, 64);
        float lse = m + logf(s);
        int rr = n0 + r0 + j;
        if (rr < NN)
            *(float4*)(out + (size_t)rr * 64 + c0) =
                make_float4(acc[j][0] - lse, acc[j][1] - lse,
                            acc[j][2] - lse, acc[j][3] - lse);
    }
}

// ---------------- host launch ----------------

static inline char* alignup(char* p, size_t a) {
    return (char*)(((uintptr_t)p + a - 1) & ~(uintptr_t)(a - 1));
}

extern "C" void kernel_launch(void* const* d_in, const int* in_sizes, int n_in,
                              void* d_out, int out_size, void* d_ws, size_t ws_size,
                              hipStream_t stream) {
    const float* x   = (const float*)d_in[0];
    const int*   ei  = (const int*)d_in[1];
    const float* W1  = (const float*)d_in[2];
    const float* b1  = (const float*)d_in[3];
    const float* W2  = (const float*)d_in[4];
    const float* b2  = (const float*)d_in[5];
    const float* Wx  = (const float*)d_in[6];
    const float* bx  = (const float*)d_in[7];
    const float* g1  = (const float*)d_in[8];
    const float* be1 = (const float*)d_in[9];
    const float* g2  = (const float*)d_in[10];
    const float* be2 = (const float*)d_in[11];
    const float* g3  = (const float*)d_in[12];
    const float* be3 = (const float*)d_in[13];
    const float* Wfc = (const float*)d_in[14];
    const float* bfc = (const float*)d_in[15];
    float* out = (float*)d_out;

    const int* srcA = ei;
    const int* dstA = ei + NE;

    char* p = (char*)d_ws;
    float* stats  = (float*)p; p += 4 * NSLICE * 128 * 4;   // 4 layers x 32 slices x 128
    int*   hist   = (int*)p;   p += NBKT * 4;
    int*   bbcur  = (int*)p;   p += 256 * 4;                // bin cursors (zeroed)
    int*   bktcur = (int*)p;   p += NBKT * 4;               // bucket cursors (zeroed)
    size_t zbytes = (size_t)(p - (char*)d_ws);
    p = alignup(p, 512);
    int*   deg   = (int*)p;    p += NN * 4;         p = alignup(p, 512);
    int*   offs  = (int*)p;    p += (NN + 4) * 4;   p = alignup(p, 512);
    float* dinv  = (float*)p;  p += NN * 4;         p = alignup(p, 512);
    int*   bsum  = (int*)p;    p += 256 * 4;        p = alignup(p, 512);
    int*   perm  = (int*)p;    p += NN * 4;         p = alignup(p, 512);
    int*   edge1 = (int*)p;    p += ((size_t)NE + 8 * NN + 256) * 4; p = alignup(p, 512);
    int2*  pairs = (int2*)p;   p += (size_t)NBIN * BCAP * 8; p = alignup(p, 512);
    float4* tmpH = (float4*)p; p += ((size_t)NN + 1) * 128; p = alignup(p, 512);
    float4* hbH  = (float4*)p; p += (size_t)NN * 128;       p = alignup(p, 512);
    float4* apH  = (float4*)p; p += (size_t)NN * 128;       p = alignup(p, 512);
    float4* pbH  = (float4*)p; p += (size_t)NN * 128;       p = alignup(p, 512);
    uint4*  x8a  = (uint4*)p;  p += ((size_t)NN + 1) * 64;  p = alignup(p, 512);
    uint4*  x8b  = (uint4*)p;  p += ((size_t)NN + 1) * 64;

    hipMemsetAsync(d_ws, 0, zbytes, stream);

    // prep (5 dispatches): binned scatter; degree/dinv/hist; fused
    // scan1+perm; fused scan2+scan3; CSR placement + pad + zrow.
    binscat_k<<<(NE + EPB - 1) / EPB, 256, 0, stream>>>(srcA, dstA, bbcur, pairs);
    bincnt_k<<<NBIN, 256, 0, stream>>>(pairs, bbcur, deg, dinv, hist);
    scan1perm_k<<<SCAN_B, 256, 0, stream>>>(deg, hist, offs, bsum, bktcur, perm);
    scan23_k<<<SCAN_B, 256, 0, stream>>>(bsum, offs);
    binplace_pad_k<<<NBIN, 256, 0, stream>>>(bbcur, pairs, offs, edge1, tmpH, x8a, x8b);

    const int MMG = (NN + 63) / 64;          // 782
    const int PG  = (NGRP + 3) / 4;          // 1563: one octet per wave
    const int AG  = (NG16 + 3) / 4;          // 782:  one 16-group per wave
    const int BNG = (NN * 8 + 255) / 256;    // 1563
    const int SL  = NSLICE * 128;            // floats per layer slice block

    // L1: mm -> prop(stats0)
    mm_k<INF_, false><<<MMG, 256, 0, stream>>>(x, W1, dinv, (float2*)tmpH);
    prop_stats_k<<<PG, 256, 0, stream>>>(tmpH, offs, edge1, dinv, b1, perm, pbH, stats + 0 * SL);
    // L2: BN(stats0,g1,be1) fused into mm(W2) -> prop(stats1)
    mm_bn_k<<<MMG, 256, 0, stream>>>(pbH, stats + 0 * SL, g1, be1, W2, dinv, (float2*)tmpH);
    prop_stats_k<<<PG, 256, 0, stream>>>(tmpH, offs, edge1, dinv, b2, perm, pbH, stats + 1 * SL);
    // L3: BN(stats1,g2,be2) fused into mm(Wx0) -> prop(stats2)
    mm_bn_k<<<MMG, 256, 0, stream>>>(pbH, stats + 1 * SL, g2, be2, Wx, dinv, (float2*)tmpH);
    prop_stats_k<<<PG, 256, 0, stream>>>(tmpH, offs, edge1, dinv, bx, perm, pbH, stats + 2 * SL);
    // L4: BN(stats2,g3,be3) fused into mm(Wx1) -> prop(stats3)
    mm_bn_k<<<MMG, 256, 0, stream>>>(pbH, stats + 2 * SL, g3, be3,
                                     Wx + (size_t)64 * 64, dinv, (float2*)tmpH);
    prop_stats_k<<<PG, 256, 0, stream>>>(tmpH, offs, edge1, dinv, bx + 64, perm,
                                         pbH, stats + 3 * SL);
    // final BN -> H0 (fp16) + fp8 seed
    bn_relu_k<<<BNG, 256, 0, stream>>>(pbH, stats + 3 * SL, g3, be3, hbH, (uint2*)x8a, dinv);

    // APPNP in fp8: 9 fp8->fp8 iters ping-pong; 10th -> fp16 apH
    const uint4* cur8 = x8a;
    for (int it = 0; it < 9; ++it) {
        uint4* o8 = (cur8 == x8a) ? x8b : x8a;
        appnp8_k<false><<<AG, 256, 0, stream>>>(cur8, hbH, offs, edge1, dinv, perm, o8, nullptr);
        cur8 = o8;
    }
    appnp8_k<true><<<AG, 256, 0, stream>>>(cur8, hbH, offs, edge1, dinv, perm, nullptr, apH);

    final_k<<<MMG, 256, 0, stream>>>((const float2*)apH, Wfc, bfc, out);
}